// Round 1
// baseline (881.984 us; speedup 1.0000x reference)
//
#include <hip/hip_runtime.h>
#include <math.h>

#define T_IN 98304
#define SS 128
#define NBATCH 2
#define NN 256          // NBATCH*SS
#define C1 256
#define C2 512
#define C3 7168
#define NCBK 14
#define DIMV 512
#define VOC 1024
#define TOUT 97537
#define HOP 768

// ws layout (float offsets)
#define OFF_CBN    0L          // 14336
#define OFF_AB1    14336L      // 512
#define OFF_AB2    14848L      // 256
#define OFF_CCONST 15104L      // 16
#define OFF_H2C    15120L      // 131072   (n*512+ic), n=b*128+s
#define OFF_H2X    146192L     // 393216   (n*1536 + ic*3 + j)
#define OFF_H3     539408L     // 1835008  (n*7168 + m)
#define OFF_SCORES 2374416L    // 3670016  ((k*256+n)*1024 + v)
#define OFF_CODES  6044432L    // 3584 ints
#define OFF_Q      6048016L    // 1835008  (n*7168 + ic)
#define OFF_A1RAW  7883024L    // 655360   ((n*5+j)*512 + c)  pre-bias/relu
#define OFF_A2ACT  8538384L    // 589824   ((n*9+u)*256 + o)  post-relu

// ---------------- prep: codebook norms ----------------
__global__ void k_cbn(const float* __restrict__ cb, float* __restrict__ cbn) {
  int row = blockIdx.x * 4 + (threadIdx.x >> 6);
  int lane = threadIdx.x & 63;
  const float* p = cb + (long)row * DIMV;
  float s = 0.f;
  for (int d = lane; d < DIMV; d += 64) { float x = p[d]; s += x * x; }
  for (int off = 32; off; off >>= 1) s += __shfl_down(s, off);
  if (lane == 0) cbn[row] = s;
}

// ---------------- prep: ab1 = relu(db1), ab2 = const a2 col, cconst ----------------
__global__ void k_prep(const float* __restrict__ db1, const float* __restrict__ dw2,
                       const float* __restrict__ db2, const float* __restrict__ dw3,
                       const float* __restrict__ db3,
                       float* __restrict__ ab1, float* __restrict__ ab2,
                       float* __restrict__ cconst) {
  __shared__ float s1[C2];
  __shared__ float s2[C1];
  __shared__ float red[256];
  int t = threadIdx.x;
  for (int c = t; c < C2; c += 256) {
    float v = fmaxf(db1[c], 0.f);
    s1[c] = v; ab1[c] = v;
  }
  __syncthreads();
  {
    int o = t;
    float acc = db2[o];
    const float* wp = dw2 + (long)o * C2 * 5;
    for (int c = 0; c < C2; ++c) {
      float wsum = wp[c*5+0] + wp[c*5+1] + wp[c*5+2] + wp[c*5+3] + wp[c*5+4];
      acc = fmaf(wsum, s1[c], acc);
    }
    float v = fmaxf(acc, 0.f);
    ab2[o] = v; s2[o] = v;
  }
  __syncthreads();
  float wsum3 = 0.f;
  #pragma unroll
  for (int j = 0; j < 7; ++j) wsum3 += dw3[t*7+j];
  red[t] = wsum3 * s2[t];
  __syncthreads();
  for (int off = 128; off; off >>= 1) {
    if (t < off) red[t] += red[t + off];
    __syncthreads();
  }
  if (t == 0) cconst[0] = tanhf(red[0] + db3[0]);
}

// ---------------- fused encoder conv1 (k7,p3) + conv2 (k5,s768,p2) ----------------
__global__ __launch_bounds__(256) void k_enc12(const float* __restrict__ audio,
    const float* __restrict__ ew1, const float* __restrict__ eb1,
    const float* __restrict__ ew2, const float* __restrict__ eb2,
    float* __restrict__ h2c) {
  __shared__ float h1s[NBATCH][5][C1];
  int s = blockIdx.x;
  int ic = threadIdx.x;
  float w1[7];
  #pragma unroll
  for (int j = 0; j < 7; ++j) w1[j] = ew1[ic*7+j];
  float b1 = eb1[ic];
  for (int b = 0; b < NBATCH; ++b) {
    const float* ap = audio + (long)b * T_IN;
    #pragma unroll
    for (int jj = 0; jj < 5; ++jj) {
      int tcol = HOP * s + jj - 2;
      float v = 0.f;
      if (tcol >= 0) {           // tcol<0 => conv2 zero padding column
        float acc = b1;
        #pragma unroll
        for (int j = 0; j < 7; ++j) {
          int ai = tcol + j - 3;
          float a = (ai >= 0 && ai < T_IN) ? ap[ai] : 0.f;
          acc = fmaf(w1[j], a, acc);
        }
        v = fmaxf(acc, 0.f);
      }
      h1s[b][jj][ic] = v;
    }
  }
  __syncthreads();
  for (int oo = 0; oo < 2; ++oo) {
    int oc = threadIdx.x + oo * 256;
    float acc0 = eb2[oc], acc1 = acc0;
    const float* wp = ew2 + (long)oc * C1 * 5;
    for (int icc = 0; icc < C1; ++icc) {
      #pragma unroll
      for (int jj = 0; jj < 5; ++jj) {
        float w = wp[icc*5+jj];
        acc0 = fmaf(w, h1s[0][jj][icc], acc0);
        acc1 = fmaf(w, h1s[1][jj][icc], acc1);
      }
    }
    h2c[(long)(0*SS + s)*C2 + oc] = fmaxf(acc0, 0.f);
    h2c[(long)(1*SS + s)*C2 + oc] = fmaxf(acc1, 0.f);
  }
}

// ---------------- im2col for conv3 (k3,p1): h2x[n][ic*3+j] ----------------
__global__ void k_h2x(const float* __restrict__ h2c, float* __restrict__ h2x) {
  int idx = blockIdx.x * 256 + threadIdx.x;
  const int total = NN * 1536;
  for (; idx < total; idx += gridDim.x * 256) {
    int n = idx / 1536, r = idx - n * 1536;
    int ic = r / 3, j = r - ic * 3;
    int s2 = (n & 127) + j - 1;
    int b = n >> 7;
    h2x[idx] = (s2 >= 0 && s2 < SS) ? h2c[(long)(b*SS + s2)*C2 + ic] : 0.f;
  }
}

#define MM16() \
  { acc[0][0]=fmaf(av.x,bv.x,acc[0][0]); acc[0][1]=fmaf(av.x,bv.y,acc[0][1]); \
    acc[0][2]=fmaf(av.x,bv.z,acc[0][2]); acc[0][3]=fmaf(av.x,bv.w,acc[0][3]); \
    acc[1][0]=fmaf(av.y,bv.x,acc[1][0]); acc[1][1]=fmaf(av.y,bv.y,acc[1][1]); \
    acc[1][2]=fmaf(av.y,bv.z,acc[1][2]); acc[1][3]=fmaf(av.y,bv.w,acc[1][3]); \
    acc[2][0]=fmaf(av.z,bv.x,acc[2][0]); acc[2][1]=fmaf(av.z,bv.y,acc[2][1]); \
    acc[2][2]=fmaf(av.z,bv.z,acc[2][2]); acc[2][3]=fmaf(av.z,bv.w,acc[2][3]); \
    acc[3][0]=fmaf(av.w,bv.x,acc[3][0]); acc[3][1]=fmaf(av.w,bv.y,acc[3][1]); \
    acc[3][2]=fmaf(av.w,bv.z,acc[3][2]); acc[3][3]=fmaf(av.w,bv.w,acc[3][3]); }

// ---------------- fp32 GEMM, A[M][K] row-major, B[N][K] row-major ----------------
// EPI 0: h3[n*C3+m] = eb3[m] + acc         (grid 56x8x1)
// EPI 1: scores[(z*256+n)*1024+m] = cbn[z*1024+m] - 2*acc   (grid 8x8x14)
template<int EPI>
__global__ __launch_bounds__(256) void gemm_nt(const float* __restrict__ A,
    const float* __restrict__ Bm, float* __restrict__ outp, int K, int lda, int ldb,
    const float* __restrict__ e1, long strideAz, long strideBz) {
  __shared__ __align__(16) float As[16][132];
  __shared__ __align__(16) float Bs[16][36];
  const int tid = threadIdx.x;
  const int z = blockIdx.z;
  const float* Ab = A + (long)z * strideAz;
  const float* Bb = Bm + (long)z * strideBz;
  const int m0 = blockIdx.x * 128, n0 = blockIdx.y * 32;
  const int mt = (tid & 31) << 2, ntc = (tid >> 5) << 2;
  const int arow = tid >> 1, akk = (tid & 1) << 3;
  const int brow = tid >> 3, bkk = (tid & 7) << 1;
  float acc[4][4] = {};
  for (int k0 = 0; k0 < K; k0 += 16) {
    const float* Ap = Ab + (long)(m0 + arow) * lda + k0 + akk;
    float4 a0 = *(const float4*)Ap;
    float4 a1 = *(const float4*)(Ap + 4);
    As[akk+0][arow] = a0.x; As[akk+1][arow] = a0.y;
    As[akk+2][arow] = a0.z; As[akk+3][arow] = a0.w;
    As[akk+4][arow] = a1.x; As[akk+5][arow] = a1.y;
    As[akk+6][arow] = a1.z; As[akk+7][arow] = a1.w;
    const float* Bp = Bb + (long)(n0 + brow) * ldb + k0 + bkk;
    float2 b0 = *(const float2*)Bp;
    Bs[bkk][brow] = b0.x; Bs[bkk+1][brow] = b0.y;
    __syncthreads();
    #pragma unroll
    for (int kk = 0; kk < 16; ++kk) {
      float4 av = *(const float4*)&As[kk][mt];
      float4 bv = *(const float4*)&Bs[kk][ntc];
      MM16();
    }
    __syncthreads();
  }
  #pragma unroll
  for (int j = 0; j < 4; ++j) {
    const int n = n0 + ntc + j;
    #pragma unroll
    for (int i = 0; i < 4; ++i) {
      const int m = m0 + mt + i;
      if (EPI == 0) outp[(long)n * C3 + m] = e1[m] + acc[i][j];
      else outp[((long)z * NN + n) * VOC + m] = e1[z * VOC + m] - 2.f * acc[i][j];
    }
  }
}

// ---------------- convT active GEMM: A = dw1 stored [K=7168][M=2560], B = q[N][K] ----
// k-split over blockIdx.z (4 x 1792), atomicAdd into a1raw (pre-zeroed)
__global__ __launch_bounds__(256) void gemm_a1(const float* __restrict__ dw1,
    const float* __restrict__ qb, float* __restrict__ a1raw) {
  __shared__ __align__(16) float As[16][132];
  __shared__ __align__(16) float Bs[16][36];
  const int tid = threadIdx.x;
  const int m0 = blockIdx.x * 128, n0 = blockIdx.y * 32;
  const int kbase = blockIdx.z * 1792;
  const int mt = (tid & 31) << 2, ntc = (tid >> 5) << 2;
  const int akk = tid >> 4;           // 0..15
  const int amj = (tid & 15) << 3;    // 0..120
  const int brow = tid >> 3, bkk = (tid & 7) << 1;
  float acc[4][4] = {};
  for (int k0 = kbase; k0 < kbase + 1792; k0 += 16) {
    const float* Ap = dw1 + (long)(k0 + akk) * 2560 + m0 + amj;
    float4 a0 = *(const float4*)Ap;
    float4 a1 = *(const float4*)(Ap + 4);
    *(float4*)&As[akk][amj] = a0;
    *(float4*)&As[akk][amj+4] = a1;
    const float* Bp = qb + (long)(n0 + brow) * C3 + k0 + bkk;
    float2 b0 = *(const float2*)Bp;
    Bs[bkk][brow] = b0.x; Bs[bkk+1][brow] = b0.y;
    __syncthreads();
    #pragma unroll
    for (int kk = 0; kk < 16; ++kk) {
      float4 av = *(const float4*)&As[kk][mt];
      float4 bv = *(const float4*)&Bs[kk][ntc];
      MM16();
    }
    __syncthreads();
  }
  #pragma unroll
  for (int j = 0; j < 4; ++j) {
    const int n = n0 + ntc + j;
    #pragma unroll
    for (int i = 0; i < 4; ++i) {
      const int m = m0 + mt + i;
      int c = m / 5, jj = m - c * 5;
      atomicAdd(&a1raw[((long)(n * 5 + jj)) * C2 + c], acc[i][j]);
    }
  }
}

// ---------------- argmin over 1024 codes, numpy tie-break (lowest v) ----------------
__global__ void k_argmin(const float* __restrict__ scores, int* __restrict__ codes) {
  int row = blockIdx.x;          // k*256+n
  int lane = threadIdx.x;        // 64
  const float* p = scores + (long)row * VOC;
  float best = 3.4e38f; int bi = 0;
  for (int i = 0; i < 16; ++i) {
    int v = i * 64 + lane;
    float x = p[v];
    if (x < best) { best = x; bi = v; }
  }
  for (int off = 32; off; off >>= 1) {
    float ob = __shfl_down(best, off);
    int oi = __shfl_down(bi, off);
    if (ob < best || (ob == best && oi < bi)) { best = ob; bi = oi; }
  }
  if (lane == 0) codes[row] = bi;
}

// ---------------- gather q[n][k*512+d] = cb[k, code, d] ----------------
__global__ void k_gather_q(const float* __restrict__ cb, const int* __restrict__ codes,
                           float* __restrict__ qb) {
  long idx = (long)blockIdx.x * 256 + threadIdx.x;
  const long total = (long)NN * C3;
  for (; idx < total; idx += (long)gridDim.x * 256) {
    int n = (int)(idx / C3);
    int r = (int)(idx - (long)n * C3);
    int k = r >> 9, d = r & 511;
    int code = codes[k * NN + n];
    qb[idx] = cb[((long)(k * VOC + code)) * DIMV + d];
  }
}

__global__ void k_zero(float* __restrict__ p, int nfl) {
  int i = blockIdx.x * 256 + threadIdx.x;
  for (; i < nfl; i += gridDim.x * 256) p[i] = 0.f;
}

// ---------------- decoder conv2 on the 9 active cols per (b,s) ----------------
__global__ __launch_bounds__(256) void k_dec2(const float* __restrict__ a1raw,
    const float* __restrict__ ab1g, const float* __restrict__ db1,
    const float* __restrict__ dw2, const float* __restrict__ db2,
    float* __restrict__ a2act) {
  __shared__ float P[C2][20];      // patch cols t = 768s-6 .. 768s+6 at [c][w]
  int n = blockIdx.x;
  int s = n & 127;
  int t = threadIdx.x;
  for (int i = t; i < 13 * C2; i += 256) {
    int w = i / C2, c = i - w * C2;
    int tc = HOP * s - 6 + w;
    float v;
    if (tc < 0 || tc > TOUT - 1) v = 0.f;
    else {
      int dj = tc - HOP * s + 2;
      if (dj >= 0 && dj <= 4)
        v = fmaxf(db1[c] + a1raw[((long)(n * 5 + dj)) * C2 + c], 0.f);
      else v = ab1g[c];
    }
    P[c][w] = v;
  }
  __syncthreads();
  int o = t;
  float acc[9];
  float bias = db2[o];
  #pragma unroll
  for (int u = 0; u < 9; ++u) acc[u] = bias;
  const float* wp = dw2 + (long)o * C2 * 5;
  for (int c = 0; c < C2; ++c) {
    float p[13];
    float4 p0 = *(const float4*)&P[c][0];
    float4 p1 = *(const float4*)&P[c][4];
    float4 p2 = *(const float4*)&P[c][8];
    p[0]=p0.x; p[1]=p0.y; p[2]=p0.z; p[3]=p0.w;
    p[4]=p1.x; p[5]=p1.y; p[6]=p1.z; p[7]=p1.w;
    p[8]=p2.x; p[9]=p2.y; p[10]=p2.z; p[11]=p2.w;
    p[12]=P[c][12];
    #pragma unroll
    for (int jj = 0; jj < 5; ++jj) {
      float w = wp[c*5+jj];
      #pragma unroll
      for (int u = 0; u < 9; ++u) acc[u] = fmaf(w, p[u + jj], acc[u]);
    }
  }
  #pragma unroll
  for (int u = 0; u < 9; ++u)
    a2act[((long)(n * 9 + u)) * C1 + o] = fmaxf(acc[u], 0.f);
}

// ---------------- fill output with the constant tanh value ----------------
__global__ void k_fill(float* __restrict__ outp, const float* __restrict__ cconst) {
  float v = cconst[0];
  int idx = blockIdx.x * 256 + threadIdx.x;
  const int total = NBATCH * TOUT;
  for (; idx < total; idx += gridDim.x * 256) outp[idx] = v;
}

// ---------------- decoder conv3+tanh on 15 active cols per (b,s) ----------------
__global__ __launch_bounds__(256) void k_dec3(const float* __restrict__ a2act,
    const float* __restrict__ ab2g, const float* __restrict__ dw3,
    const float* __restrict__ db3, float* __restrict__ outp) {
  __shared__ float sa2[9 * C1];
  __shared__ float sb[C1];
  int n = blockIdx.x;
  int s = n & 127, b = n >> 7;
  int t = threadIdx.x;
  for (int i = t; i < 9 * C1; i += 256) sa2[i] = a2act[(long)n * 9 * C1 + i];
  sb[t] = ab2g[t];
  __syncthreads();
  int wv = t >> 6, lane = t & 63;
  float b3 = db3[0];
  for (int w15 = wv; w15 < 15; w15 += 4) {
    int tc = HOP * s - 7 + w15;
    if (tc < 0 || tc > TOUT - 1) continue;   // block/wave-uniform
    float part = 0.f;
    for (int cc = lane; cc < C1; cc += 64) {
      #pragma unroll
      for (int j = 0; j < 7; ++j) {
        int wcol = tc + j - 3;
        float x;
        if (wcol < 0 || wcol > TOUT - 1) x = 0.f;
        else {
          int du = wcol - (HOP * s - 4);
          x = (du >= 0 && du <= 8) ? sa2[du * C1 + cc] : sb[cc];
        }
        part = fmaf(dw3[cc*7+j], x, part);
      }
    }
    for (int off = 32; off; off >>= 1) part += __shfl_down(part, off);
    if (lane == 0) outp[(long)b * TOUT + tc] = tanhf(part + b3);
  }
}

extern "C" void kernel_launch(void* const* d_in, const int* in_sizes, int n_in,
                              void* d_out, int out_size, void* d_ws, size_t ws_size,
                              hipStream_t stream) {
  const float* audio = (const float*)d_in[0];
  const float* cb    = (const float*)d_in[1];
  const float* ew1   = (const float*)d_in[2];
  const float* eb1   = (const float*)d_in[3];
  const float* ew2   = (const float*)d_in[4];
  const float* eb2   = (const float*)d_in[5];
  const float* ew3   = (const float*)d_in[6];
  const float* eb3   = (const float*)d_in[7];
  const float* dw1   = (const float*)d_in[8];
  const float* db1   = (const float*)d_in[9];
  const float* dw2   = (const float*)d_in[10];
  const float* db2   = (const float*)d_in[11];
  const float* dw3   = (const float*)d_in[12];
  const float* db3   = (const float*)d_in[13];
  float* outp = (float*)d_out;
  float* ws = (float*)d_ws;

  float* cbn    = ws + OFF_CBN;
  float* ab1    = ws + OFF_AB1;
  float* ab2    = ws + OFF_AB2;
  float* cconst = ws + OFF_CCONST;
  float* h2c    = ws + OFF_H2C;
  float* h2x    = ws + OFF_H2X;
  float* h3     = ws + OFF_H3;
  float* scores = ws + OFF_SCORES;
  int*   codes  = (int*)(ws + OFF_CODES);
  float* qb     = ws + OFF_Q;
  float* a1raw  = ws + OFF_A1RAW;
  float* a2act  = ws + OFF_A2ACT;

  k_cbn<<<3584, 256, 0, stream>>>(cb, cbn);
  k_prep<<<1, 256, 0, stream>>>(db1, dw2, db2, dw3, db3, ab1, ab2, cconst);
  k_enc12<<<SS, 256, 0, stream>>>(audio, ew1, eb1, ew2, eb2, h2c);
  k_h2x<<<384, 256, 0, stream>>>(h2c, h2x);
  gemm_nt<0><<<dim3(56, 8, 1), 256, 0, stream>>>(ew3, h2x, h3, 1536, 1536, 1536, eb3, 0L, 0L);
  gemm_nt<1><<<dim3(8, 8, 14), 256, 0, stream>>>(cb, h3, scores, 512, 512, 7168,
                                                 cbn, (long)VOC * DIMV, 512L);
  k_argmin<<<NCBK * NN, 64, 0, stream>>>(scores, codes);
  k_gather_q<<<1792, 256, 0, stream>>>(cb, codes, qb);
  k_zero<<<640, 256, 0, stream>>>(a1raw, 655360);
  gemm_a1<<<dim3(20, 8, 4), 256, 0, stream>>>(dw1, qb, a1raw);
  k_dec2<<<NN, 256, 0, stream>>>(a1raw, ab1, db1, dw2, db2, a2act);
  k_fill<<<256, 256, 0, stream>>>(outp, cconst);
  k_dec3<<<NN, 256, 0, stream>>>(a2act, ab2, dw3, db3, outp);
}

// Round 2
// 861.412 us; speedup vs baseline: 1.0239x; 1.0239x over previous
//
#include <hip/hip_runtime.h>
#include <hip/hip_bf16.h>
#include <math.h>

#define T_IN 98304
#define SS 128
#define NBATCH 2
#define NN 256          // NBATCH*SS
#define C1 256
#define C2 512
#define C3 7168
#define NCBK 14
#define DIMV 512
#define VOC 1024
#define TOUT 97537
#define HOP 768

// ws layout (float offsets)
#define OFF_CBN    0L          // 14336
#define OFF_AB1    14336L      // 512
#define OFF_AB2    14848L      // 256
#define OFF_CCONST 15104L      // 16
#define OFF_H2C    15120L      // 131072   (n*512+ic), n=b*128+s
#define OFF_H2X    146192L     // 393216   (n*1536 + ic*3 + j)
#define OFF_H3     539408L     // 1835008  (n*7168 + m)
#define OFF_SCORES 2374416L    // 3670016  ((k*256+n)*1024 + v)
// dw1t (bf16 [2560][7168], 9175040 float slots) OVERLAPS h3+scores: both dead
// before k_dw1t runs (launched after k_argmin; same stream serializes).
#define OFF_DW1T   539408L     // ends 9714448
#define OFF_CODES  9714448L    // 3584 ints
#define OFF_QBF    9718032L    // 917504 float slots (bf16 [256][7168])
#define OFF_A1RAW  10635536L   // 655360   ((n*5+j)*512 + c)  pre-bias/relu
#define OFF_A2ACT  11290896L   // 589824   ((n*9+u)*256 + o)  post-relu
// total 11880720 floats = 47.5 MB

typedef __attribute__((ext_vector_type(8))) short short8;
typedef __attribute__((ext_vector_type(4))) float f32x4;

static __device__ inline ushort f2bf(float x) {
  __hip_bfloat16 h = __float2bfloat16(x);
  return *reinterpret_cast<ushort*>(&h);
}

// ---------------- prep: codebook norms ----------------
__global__ void k_cbn(const float* __restrict__ cb, float* __restrict__ cbn) {
  int row = blockIdx.x * 4 + (threadIdx.x >> 6);
  int lane = threadIdx.x & 63;
  const float* p = cb + (long)row * DIMV;
  float s = 0.f;
  for (int d = lane; d < DIMV; d += 64) { float x = p[d]; s += x * x; }
  for (int off = 32; off; off >>= 1) s += __shfl_down(s, off);
  if (lane == 0) cbn[row] = s;
}

// ---------------- prep: ab1 = relu(db1), ab2 = const a2 col, cconst ----------------
__global__ void k_prep(const float* __restrict__ db1, const float* __restrict__ dw2,
                       const float* __restrict__ db2, const float* __restrict__ dw3,
                       const float* __restrict__ db3,
                       float* __restrict__ ab1, float* __restrict__ ab2,
                       float* __restrict__ cconst) {
  __shared__ float s1[C2];
  __shared__ float s2[C1];
  __shared__ float red[256];
  int t = threadIdx.x;
  for (int c = t; c < C2; c += 256) {
    float v = fmaxf(db1[c], 0.f);
    s1[c] = v; ab1[c] = v;
  }
  __syncthreads();
  {
    int o = t;
    float acc = db2[o];
    const float* wp = dw2 + (long)o * C2 * 5;
    for (int c = 0; c < C2; ++c) {
      float wsum = wp[c*5+0] + wp[c*5+1] + wp[c*5+2] + wp[c*5+3] + wp[c*5+4];
      acc = fmaf(wsum, s1[c], acc);
    }
    float v = fmaxf(acc, 0.f);
    ab2[o] = v; s2[o] = v;
  }
  __syncthreads();
  float wsum3 = 0.f;
  #pragma unroll
  for (int j = 0; j < 7; ++j) wsum3 += dw3[t*7+j];
  red[t] = wsum3 * s2[t];
  __syncthreads();
  for (int off = 128; off; off >>= 1) {
    if (t < off) red[t] += red[t + off];
    __syncthreads();
  }
  if (t == 0) cconst[0] = tanhf(red[0] + db3[0]);
}

// ---------------- fused encoder conv1 (k7,p3) + conv2 (k5,s768,p2) ----------------
__global__ __launch_bounds__(256) void k_enc12(const float* __restrict__ audio,
    const float* __restrict__ ew1, const float* __restrict__ eb1,
    const float* __restrict__ ew2, const float* __restrict__ eb2,
    float* __restrict__ h2c) {
  __shared__ float h1s[NBATCH][5][C1];
  int s = blockIdx.x;
  int ic = threadIdx.x;
  float w1[7];
  #pragma unroll
  for (int j = 0; j < 7; ++j) w1[j] = ew1[ic*7+j];
  float b1 = eb1[ic];
  for (int b = 0; b < NBATCH; ++b) {
    const float* ap = audio + (long)b * T_IN;
    #pragma unroll
    for (int jj = 0; jj < 5; ++jj) {
      int tcol = HOP * s + jj - 2;
      float v = 0.f;
      if (tcol >= 0) {
        float acc = b1;
        #pragma unroll
        for (int j = 0; j < 7; ++j) {
          int ai = tcol + j - 3;
          float a = (ai >= 0 && ai < T_IN) ? ap[ai] : 0.f;
          acc = fmaf(w1[j], a, acc);
        }
        v = fmaxf(acc, 0.f);
      }
      h1s[b][jj][ic] = v;
    }
  }
  __syncthreads();
  for (int oo = 0; oo < 2; ++oo) {
    int oc = threadIdx.x + oo * 256;
    float acc0 = eb2[oc], acc1 = acc0;
    const float* wp = ew2 + (long)oc * C1 * 5;
    for (int icc = 0; icc < C1; ++icc) {
      #pragma unroll
      for (int jj = 0; jj < 5; ++jj) {
        float w = wp[icc*5+jj];
        acc0 = fmaf(w, h1s[0][jj][icc], acc0);
        acc1 = fmaf(w, h1s[1][jj][icc], acc1);
      }
    }
    h2c[(long)(0*SS + s)*C2 + oc] = fmaxf(acc0, 0.f);
    h2c[(long)(1*SS + s)*C2 + oc] = fmaxf(acc1, 0.f);
  }
}

// ---------------- im2col for conv3 (k3,p1): h2x[n][ic*3+j] ----------------
__global__ void k_h2x(const float* __restrict__ h2c, float* __restrict__ h2x) {
  int idx = blockIdx.x * 256 + threadIdx.x;
  const int total = NN * 1536;
  for (; idx < total; idx += gridDim.x * 256) {
    int n = idx / 1536, r = idx - n * 1536;
    int ic = r / 3, j = r - ic * 3;
    int s2 = (n & 127) + j - 1;
    int b = n >> 7;
    h2x[idx] = (s2 >= 0 && s2 < SS) ? h2c[(long)(b*SS + s2)*C2 + ic] : 0.f;
  }
}

#define FMA44(ACC, AV, BV) \
  { ACC[0][0]=fmaf(AV.x,BV.x,ACC[0][0]); ACC[0][1]=fmaf(AV.x,BV.y,ACC[0][1]); \
    ACC[0][2]=fmaf(AV.x,BV.z,ACC[0][2]); ACC[0][3]=fmaf(AV.x,BV.w,ACC[0][3]); \
    ACC[1][0]=fmaf(AV.y,BV.x,ACC[1][0]); ACC[1][1]=fmaf(AV.y,BV.y,ACC[1][1]); \
    ACC[1][2]=fmaf(AV.y,BV.z,ACC[1][2]); ACC[1][3]=fmaf(AV.y,BV.w,ACC[1][3]); \
    ACC[2][0]=fmaf(AV.z,BV.x,ACC[2][0]); ACC[2][1]=fmaf(AV.z,BV.y,ACC[2][1]); \
    ACC[2][2]=fmaf(AV.z,BV.z,ACC[2][2]); ACC[2][3]=fmaf(AV.z,BV.w,ACC[2][3]); \
    ACC[3][0]=fmaf(AV.w,BV.x,ACC[3][0]); ACC[3][1]=fmaf(AV.w,BV.y,ACC[3][1]); \
    ACC[3][2]=fmaf(AV.w,BV.z,ACC[3][2]); ACC[3][3]=fmaf(AV.w,BV.w,ACC[3][3]); }

// ---------------- fp32 GEMM, A[M][K] row-major, B[N][K] row-major ----------------
// BM=128, BN=64, BK=16; per thread 8m x 4n (two 4-row m-strips 64 apart)
// EPI 0: h3[n*C3+m] = eb3[m] + acc         (grid 56x4x1)
// EPI 1: scores[(z*256+n)*1024+m] = cbn[z*1024+m] - 2*acc   (grid 8x4x14)
template<int EPI>
__global__ __launch_bounds__(256) void gemm_nt(const float* __restrict__ A,
    const float* __restrict__ Bm, float* __restrict__ outp, int K, int lda, int ldb,
    const float* __restrict__ e1, long strideAz, long strideBz) {
  __shared__ __align__(16) float As[16][132];
  __shared__ __align__(16) float Bs[16][68];
  const int tid = threadIdx.x;
  const int z = blockIdx.z;
  const float* Ab = A + (long)z * strideAz;
  const float* Bb = Bm + (long)z * strideBz;
  const int m0 = blockIdx.x * 128, n0 = blockIdx.y * 64;
  const int mt = (tid & 15) << 2, nt = (tid >> 4) << 2;
  const int arow = tid >> 1, akk = (tid & 1) << 3;
  const int brow = tid >> 2, bkk = (tid & 3) << 2;
  float acc0[4][4] = {};
  float acc1[4][4] = {};
  for (int k0 = 0; k0 < K; k0 += 16) {
    const float* Ap = Ab + (long)(m0 + arow) * lda + k0 + akk;
    float4 a0 = *(const float4*)Ap;
    float4 a1 = *(const float4*)(Ap + 4);
    As[akk+0][arow] = a0.x; As[akk+1][arow] = a0.y;
    As[akk+2][arow] = a0.z; As[akk+3][arow] = a0.w;
    As[akk+4][arow] = a1.x; As[akk+5][arow] = a1.y;
    As[akk+6][arow] = a1.z; As[akk+7][arow] = a1.w;
    const float* Bp = Bb + (long)(n0 + brow) * ldb + k0 + bkk;
    float4 b0 = *(const float4*)Bp;
    Bs[bkk+0][brow] = b0.x; Bs[bkk+1][brow] = b0.y;
    Bs[bkk+2][brow] = b0.z; Bs[bkk+3][brow] = b0.w;
    __syncthreads();
    #pragma unroll
    for (int kk = 0; kk < 16; ++kk) {
      float4 av0 = *(const float4*)&As[kk][mt];
      float4 av1 = *(const float4*)&As[kk][mt + 64];
      float4 bv  = *(const float4*)&Bs[kk][nt];
      FMA44(acc0, av0, bv);
      FMA44(acc1, av1, bv);
    }
    __syncthreads();
  }
  #pragma unroll
  for (int j = 0; j < 4; ++j) {
    const int n = n0 + nt + j;
    #pragma unroll
    for (int i = 0; i < 4; ++i) {
      {
        const int m = m0 + mt + i;
        if (EPI == 0) outp[(long)n * C3 + m] = e1[m] + acc0[i][j];
        else outp[((long)z * NN + n) * VOC + m] = e1[z * VOC + m] - 2.f * acc0[i][j];
      }
      {
        const int m = m0 + 64 + mt + i;
        if (EPI == 0) outp[(long)n * C3 + m] = e1[m] + acc1[i][j];
        else outp[((long)z * NN + n) * VOC + m] = e1[z * VOC + m] - 2.f * acc1[i][j];
      }
    }
  }
}

// ---------------- argmin over 1024 codes, numpy tie-break (lowest v) ----------------
__global__ void k_argmin(const float* __restrict__ scores, int* __restrict__ codes) {
  int row = blockIdx.x;          // k*256+n
  int lane = threadIdx.x;        // 64
  const float* p = scores + (long)row * VOC;
  float best = 3.4e38f; int bi = 0;
  for (int i = 0; i < 16; ++i) {
    int v = i * 64 + lane;
    float x = p[v];
    if (x < best) { best = x; bi = v; }
  }
  for (int off = 32; off; off >>= 1) {
    float ob = __shfl_down(best, off);
    int oi = __shfl_down(bi, off);
    if (ob < best || (ob == best && oi < bi)) { best = ob; bi = oi; }
  }
  if (lane == 0) codes[row] = bi;
}

// ---------------- transpose+convert dw1 [7168][2560] fp32 -> dw1t [2560][7168] bf16 ----
__global__ __launch_bounds__(256) void k_dw1t(const float* __restrict__ dw1,
                                              ushort* __restrict__ dw1t) {
  __shared__ __align__(16) ushort T[64 * 72];   // [m][k] tile, pitch 72
  int t = threadIdx.x;
  int k0 = blockIdx.x * 64, m0 = blockIdx.y * 64;
  int kk = t >> 2, mj = (t & 3) * 16;
  const float* src = dw1 + (long)(k0 + kk) * 2560 + m0 + mj;
  float x[16];
  *(float4*)&x[0]  = *(const float4*)(src);
  *(float4*)&x[4]  = *(const float4*)(src + 4);
  *(float4*)&x[8]  = *(const float4*)(src + 8);
  *(float4*)&x[12] = *(const float4*)(src + 12);
  #pragma unroll
  for (int l = 0; l < 16; ++l)
    T[(mj + l) * 72 + kk] = f2bf(x[l]);
  __syncthreads();
  int mo = t >> 2, kc = (t & 3) * 16;
  uint4 u0 = *(const uint4*)&T[mo * 72 + kc];
  uint4 u1 = *(const uint4*)&T[mo * 72 + kc + 8];
  ushort* dst = dw1t + (long)(m0 + mo) * C3 + k0 + kc;
  *(uint4*)dst = u0;
  *(uint4*)(dst + 8) = u1;
}

// ---------------- gather q as bf16: qbf[n][k*512+d] = bf16(cb[k, code, d]) ----------
__global__ void k_gather_qbf(const float* __restrict__ cb, const int* __restrict__ codes,
                             ushort* __restrict__ qbf) {
  int idx = blockIdx.x * 256 + threadIdx.x;      // pair index
  const int total = NN * C3 / 2;                 // 917504
  if (idx >= total) return;
  int n = idx / 3584, rr = idx - n * 3584;       // rr = k*256 + dp
  int k = rr >> 8, dp = rr & 255;
  int code = codes[k * NN + n];
  const float* s = cb + ((long)(k * VOC + code)) * DIMV + dp * 2;
  uint lo = f2bf(s[0]), hi = f2bf(s[1]);
  ((uint*)qbf)[idx] = lo | (hi << 16);
}

// ---------------- decoder convT GEMM via MFMA bf16 ----------------
// a1raw[m=c*5+jj][n] = sum_k dw1t[m][k] * qbf[n][k];  64x64 tile, 4 waves 2x2 mfma
__global__ __launch_bounds__(256) void gemm_a1_mfma(const ushort* __restrict__ dw1t,
    const ushort* __restrict__ qbf, float* __restrict__ a1raw) {
  __shared__ __align__(16) ushort As[64 * 32];   // [m][k]
  __shared__ __align__(16) ushort Bs[64 * 32];   // [n][k]
  const int tid = threadIdx.x;
  const int w = tid >> 6, lane = tid & 63;
  const int wm = w & 1, wn = w >> 1;
  const int m0 = blockIdx.x * 64, n0 = blockIdx.y * 64;
  const int l15 = lane & 15, quad = lane >> 4;
  const int r = tid >> 2, koff = (tid & 3) * 8;
  const ushort* aP = dw1t + (long)(m0 + r) * C3 + koff;
  const ushort* bP = qbf + (long)(n0 + r) * C3 + koff;
  f32x4 acc[2][2] = {};
  const int aoff0 = (wm * 32 + l15) * 32 + quad * 8;
  const int aoff1 = (wm * 32 + 16 + l15) * 32 + quad * 8;
  const int boff0 = (wn * 32 + l15) * 32 + quad * 8;
  const int boff1 = (wn * 32 + 16 + l15) * 32 + quad * 8;
  for (int k0 = 0; k0 < C3; k0 += 32) {
    uint4 av = *(const uint4*)(aP + k0);
    uint4 bv = *(const uint4*)(bP + k0);
    *(uint4*)&As[tid * 8] = av;
    *(uint4*)&Bs[tid * 8] = bv;
    __syncthreads();
    short8 a0 = *(const short8*)&As[aoff0];
    short8 a1 = *(const short8*)&As[aoff1];
    short8 b0 = *(const short8*)&Bs[boff0];
    short8 b1 = *(const short8*)&Bs[boff1];
    acc[0][0] = __builtin_amdgcn_mfma_f32_16x16x32_bf16(a0, b0, acc[0][0], 0, 0, 0);
    acc[0][1] = __builtin_amdgcn_mfma_f32_16x16x32_bf16(a0, b1, acc[0][1], 0, 0, 0);
    acc[1][0] = __builtin_amdgcn_mfma_f32_16x16x32_bf16(a1, b0, acc[1][0], 0, 0, 0);
    acc[1][1] = __builtin_amdgcn_mfma_f32_16x16x32_bf16(a1, b1, acc[1][1], 0, 0, 0);
    __syncthreads();
  }
  #pragma unroll
  for (int i = 0; i < 2; ++i)
    #pragma unroll
    for (int j = 0; j < 2; ++j)
      #pragma unroll
      for (int reg = 0; reg < 4; ++reg) {
        int m = m0 + wm * 32 + i * 16 + quad * 4 + reg;
        int n = n0 + wn * 32 + j * 16 + l15;
        int c = m / 5, jj = m - c * 5;
        a1raw[((long)(n * 5 + jj)) * C2 + c] = acc[i][j][reg];
      }
}

// ---------------- decoder conv2 on the 9 active cols per (b,s) ----------------
__global__ __launch_bounds__(256) void k_dec2(const float* __restrict__ a1raw,
    const float* __restrict__ ab1g, const float* __restrict__ db1,
    const float* __restrict__ dw2, const float* __restrict__ db2,
    float* __restrict__ a2act) {
  __shared__ float P[C2][20];
  int n = blockIdx.x;
  int s = n & 127;
  int t = threadIdx.x;
  for (int i = t; i < 13 * C2; i += 256) {
    int w = i / C2, c = i - w * C2;
    int tc = HOP * s - 6 + w;
    float v;
    if (tc < 0 || tc > TOUT - 1) v = 0.f;
    else {
      int dj = tc - HOP * s + 2;
      if (dj >= 0 && dj <= 4)
        v = fmaxf(db1[c] + a1raw[((long)(n * 5 + dj)) * C2 + c], 0.f);
      else v = ab1g[c];
    }
    P[c][w] = v;
  }
  __syncthreads();
  int o = t;
  float acc[9];
  float bias = db2[o];
  #pragma unroll
  for (int u = 0; u < 9; ++u) acc[u] = bias;
  const float* wp = dw2 + (long)o * C2 * 5;
  for (int c = 0; c < C2; ++c) {
    float p[13];
    float4 p0 = *(const float4*)&P[c][0];
    float4 p1 = *(const float4*)&P[c][4];
    float4 p2 = *(const float4*)&P[c][8];
    p[0]=p0.x; p[1]=p0.y; p[2]=p0.z; p[3]=p0.w;
    p[4]=p1.x; p[5]=p1.y; p[6]=p1.z; p[7]=p1.w;
    p[8]=p2.x; p[9]=p2.y; p[10]=p2.z; p[11]=p2.w;
    p[12]=P[c][12];
    #pragma unroll
    for (int jj = 0; jj < 5; ++jj) {
      float w = wp[c*5+jj];
      #pragma unroll
      for (int u = 0; u < 9; ++u) acc[u] = fmaf(w, p[u + jj], acc[u]);
    }
  }
  #pragma unroll
  for (int u = 0; u < 9; ++u)
    a2act[((long)(n * 9 + u)) * C1 + o] = fmaxf(acc[u], 0.f);
}

// ---------------- fill output with the constant tanh value ----------------
__global__ void k_fill(float* __restrict__ outp, const float* __restrict__ cconst) {
  float v = cconst[0];
  int idx = blockIdx.x * 256 + threadIdx.x;
  const int total = NBATCH * TOUT;
  for (; idx < total; idx += gridDim.x * 256) outp[idx] = v;
}

// ---------------- decoder conv3+tanh on 15 active cols per (b,s) ----------------
__global__ __launch_bounds__(256) void k_dec3(const float* __restrict__ a2act,
    const float* __restrict__ ab2g, const float* __restrict__ dw3,
    const float* __restrict__ db3, float* __restrict__ outp) {
  __shared__ float sa2[9 * C1];
  __shared__ float sb[C1];
  int n = blockIdx.x;
  int s = n & 127, b = n >> 7;
  int t = threadIdx.x;
  for (int i = t; i < 9 * C1; i += 256) sa2[i] = a2act[(long)n * 9 * C1 + i];
  sb[t] = ab2g[t];
  __syncthreads();
  int wv = t >> 6, lane = t & 63;
  float b3 = db3[0];
  for (int w15 = wv; w15 < 15; w15 += 4) {
    int tc = HOP * s - 7 + w15;
    if (tc < 0 || tc > TOUT - 1) continue;
    float part = 0.f;
    for (int cc = lane; cc < C1; cc += 64) {
      #pragma unroll
      for (int j = 0; j < 7; ++j) {
        int wcol = tc + j - 3;
        float x;
        if (wcol < 0 || wcol > TOUT - 1) x = 0.f;
        else {
          int du = wcol - (HOP * s - 4);
          x = (du >= 0 && du <= 8) ? sa2[du * C1 + cc] : sb[cc];
        }
        part = fmaf(dw3[cc*7+j], x, part);
      }
    }
    for (int off = 32; off; off >>= 1) part += __shfl_down(part, off);
    if (lane == 0) outp[(long)b * TOUT + tc] = tanhf(part + b3);
  }
}

extern "C" void kernel_launch(void* const* d_in, const int* in_sizes, int n_in,
                              void* d_out, int out_size, void* d_ws, size_t ws_size,
                              hipStream_t stream) {
  const float* audio = (const float*)d_in[0];
  const float* cb    = (const float*)d_in[1];
  const float* ew1   = (const float*)d_in[2];
  const float* eb1   = (const float*)d_in[3];
  const float* ew2   = (const float*)d_in[4];
  const float* eb2   = (const float*)d_in[5];
  const float* ew3   = (const float*)d_in[6];
  const float* eb3   = (const float*)d_in[7];
  const float* dw1   = (const float*)d_in[8];
  const float* db1   = (const float*)d_in[9];
  const float* dw2   = (const float*)d_in[10];
  const float* db2   = (const float*)d_in[11];
  const float* dw3   = (const float*)d_in[12];
  const float* db3   = (const float*)d_in[13];
  float* outp = (float*)d_out;
  float* ws = (float*)d_ws;

  float*  cbn    = ws + OFF_CBN;
  float*  ab1    = ws + OFF_AB1;
  float*  ab2    = ws + OFF_AB2;
  float*  cconst = ws + OFF_CCONST;
  float*  h2c    = ws + OFF_H2C;
  float*  h2x    = ws + OFF_H2X;
  float*  h3     = ws + OFF_H3;
  float*  scores = ws + OFF_SCORES;
  ushort* dw1t   = (ushort*)(ws + OFF_DW1T);
  int*    codes  = (int*)(ws + OFF_CODES);
  ushort* qbf    = (ushort*)(ws + OFF_QBF);
  float*  a1raw  = ws + OFF_A1RAW;
  float*  a2act  = ws + OFF_A2ACT;

  k_cbn<<<3584, 256, 0, stream>>>(cb, cbn);
  k_prep<<<1, 256, 0, stream>>>(db1, dw2, db2, dw3, db3, ab1, ab2, cconst);
  k_enc12<<<SS, 256, 0, stream>>>(audio, ew1, eb1, ew2, eb2, h2c);
  k_h2x<<<384, 256, 0, stream>>>(h2c, h2x);
  gemm_nt<0><<<dim3(56, 4, 1), 256, 0, stream>>>(ew3, h2x, h3, 1536, 1536, 1536, eb3, 0L, 0L);
  gemm_nt<1><<<dim3(8, 4, 14), 256, 0, stream>>>(cb, h3, scores, 512, 512, 7168,
                                                 cbn, (long)VOC * DIMV, 512L);
  k_argmin<<<NCBK * NN, 64, 0, stream>>>(scores, codes);
  // dw1t overlaps h3/scores memory: must launch AFTER k_argmin (stream-ordered)
  k_dw1t<<<dim3(112, 40), 256, 0, stream>>>(dw1, dw1t);
  k_gather_qbf<<<3584, 256, 0, stream>>>(cb, codes, qbf);
  gemm_a1_mfma<<<dim3(40, 4), 256, 0, stream>>>(dw1t, qbf, a1raw);
  k_dec2<<<NN, 256, 0, stream>>>(a1raw, ab1, db1, dw2, db2, a2act);
  k_fill<<<256, 256, 0, stream>>>(outp, cconst);
  k_dec3<<<NN, 256, 0, stream>>>(a2act, ab2, dw3, db3, outp);
}

// Round 3
// 760.966 us; speedup vs baseline: 1.1590x; 1.1320x over previous
//
#include <hip/hip_runtime.h>
#include <hip/hip_bf16.h>
#include <math.h>

#define T_IN 98304
#define SS 128
#define NBATCH 2
#define NN 256          // NBATCH*SS
#define C1 256
#define C2 512
#define C3 7168
#define NCBK 14
#define DIMV 512
#define VOC 1024
#define TOUT 97537
#define HOP 768

// ws layout (float offsets)
#define OFF_CBN    0L          // 14336
#define OFF_AB1    14336L      // 512
#define OFF_AB2    14848L      // 256
#define OFF_CCONST 15104L      // 16
#define OFF_H2C    15120L      // 131072   (n*512+ic), n=b*128+s
#define OFF_H2XH   146192L     // 196608 fl (ushort [256][1536] bf16-hi)
#define OFF_H2XL   342800L     // 196608 fl (bf16-lo)
#define OFF_H3H    539408L     // 917504 fl (ushort [256][7168] bf16-hi)
#define OFF_H3L    1456912L    // 917504 fl
#define OFF_SCORES 2374416L    // 3670016  ((k*256+n)*1024 + v)
// dw1t (bf16 [2560][7168] = 9175040 fl) OVERLAPS h3h/h3l/scores: all dead
// before k_dw1t runs (launched after k_argmin; same stream serializes).
#define OFF_DW1T   539408L     // ends 9714448
#define OFF_CODES  9714448L    // 3584 ints
#define OFF_QBF    9718032L    // 917504 fl (bf16 [256][7168])
#define OFF_A1RAW  10635536L   // 655360   ((n*5+j)*512 + c)  pre-bias/relu
#define OFF_A2ACT  11290896L   // 589824   ((n*9+u)*256 + o)  post-relu
// total 11880720 floats = 47.5 MB (same as R2, which fit)

typedef __attribute__((ext_vector_type(8))) short short8;
typedef __attribute__((ext_vector_type(4))) float f32x4;

static __device__ inline ushort f2bf(float x) {
  __hip_bfloat16 h = __float2bfloat16(x);
  return *reinterpret_cast<ushort*>(&h);
}

// exact 2-term split: x = hi + lo + O(2^-16 |x|); truncation split, residual exact
static __device__ inline void split8(const float4 x0, const float4 x1,
                                     short8& h, short8& l) {
  float xs[8] = {x0.x, x0.y, x0.z, x0.w, x1.x, x1.y, x1.z, x1.w};
  #pragma unroll
  for (int e = 0; e < 8; ++e) {
    uint b = __float_as_uint(xs[e]);
    h[e] = (short)(b >> 16);
    float r = xs[e] - __uint_as_float(b & 0xffff0000u);
    l[e] = (short)(__float_as_uint(r) >> 16);
  }
}

// ---------------- prep: codebook norms ----------------
__global__ void k_cbn(const float* __restrict__ cb, float* __restrict__ cbn) {
  int row = blockIdx.x * 4 + (threadIdx.x >> 6);
  int lane = threadIdx.x & 63;
  const float* p = cb + (long)row * DIMV;
  float s = 0.f;
  for (int d = lane; d < DIMV; d += 64) { float x = p[d]; s += x * x; }
  for (int off = 32; off; off >>= 1) s += __shfl_down(s, off);
  if (lane == 0) cbn[row] = s;
}

// ---------------- prep: ab1 = relu(db1), ab2 = const a2 col, cconst ----------------
__global__ void k_prep(const float* __restrict__ db1, const float* __restrict__ dw2,
                       const float* __restrict__ db2, const float* __restrict__ dw3,
                       const float* __restrict__ db3,
                       float* __restrict__ ab1, float* __restrict__ ab2,
                       float* __restrict__ cconst) {
  __shared__ float s1[C2];
  __shared__ float s2[C1];
  __shared__ float red[256];
  int t = threadIdx.x;
  for (int c = t; c < C2; c += 256) {
    float v = fmaxf(db1[c], 0.f);
    s1[c] = v; ab1[c] = v;
  }
  __syncthreads();
  {
    int o = t;
    float acc = db2[o];
    const float* wp = dw2 + (long)o * C2 * 5;
    for (int c = 0; c < C2; ++c) {
      float wsum = wp[c*5+0] + wp[c*5+1] + wp[c*5+2] + wp[c*5+3] + wp[c*5+4];
      acc = fmaf(wsum, s1[c], acc);
    }
    float v = fmaxf(acc, 0.f);
    ab2[o] = v; s2[o] = v;
  }
  __syncthreads();
  float wsum3 = 0.f;
  #pragma unroll
  for (int j = 0; j < 7; ++j) wsum3 += dw3[t*7+j];
  red[t] = wsum3 * s2[t];
  __syncthreads();
  for (int off = 128; off; off >>= 1) {
    if (t < off) red[t] += red[t + off];
    __syncthreads();
  }
  if (t == 0) cconst[0] = tanhf(red[0] + db3[0]);
}

// ---------------- fused encoder conv1 (k7,p3) + conv2 (k5,s768,p2) ----------------
__global__ __launch_bounds__(256) void k_enc12(const float* __restrict__ audio,
    const float* __restrict__ ew1, const float* __restrict__ eb1,
    const float* __restrict__ ew2, const float* __restrict__ eb2,
    float* __restrict__ h2c) {
  __shared__ float h1s[NBATCH][5][C1];
  int s = blockIdx.x;
  int ic = threadIdx.x;
  float w1[7];
  #pragma unroll
  for (int j = 0; j < 7; ++j) w1[j] = ew1[ic*7+j];
  float b1 = eb1[ic];
  for (int b = 0; b < NBATCH; ++b) {
    const float* ap = audio + (long)b * T_IN;
    #pragma unroll
    for (int jj = 0; jj < 5; ++jj) {
      int tcol = HOP * s + jj - 2;
      float v = 0.f;
      if (tcol >= 0) {
        float acc = b1;
        #pragma unroll
        for (int j = 0; j < 7; ++j) {
          int ai = tcol + j - 3;
          float a = (ai >= 0 && ai < T_IN) ? ap[ai] : 0.f;
          acc = fmaf(w1[j], a, acc);
        }
        v = fmaxf(acc, 0.f);
      }
      h1s[b][jj][ic] = v;
    }
  }
  __syncthreads();
  for (int oo = 0; oo < 2; ++oo) {
    int oc = threadIdx.x + oo * 256;
    float acc0 = eb2[oc], acc1 = acc0;
    const float* wp = ew2 + (long)oc * C1 * 5;
    for (int icc = 0; icc < C1; ++icc) {
      #pragma unroll
      for (int jj = 0; jj < 5; ++jj) {
        float w = wp[icc*5+jj];
        acc0 = fmaf(w, h1s[0][jj][icc], acc0);
        acc1 = fmaf(w, h1s[1][jj][icc], acc1);
      }
    }
    h2c[(long)(0*SS + s)*C2 + oc] = fmaxf(acc0, 0.f);
    h2c[(long)(1*SS + s)*C2 + oc] = fmaxf(acc1, 0.f);
  }
}

// ---------------- im2col for conv3 (k3,p1), written as bf16 hi/lo split ----------
__global__ void k_h2x(const float* __restrict__ h2c, ushort* __restrict__ h2xh,
                      ushort* __restrict__ h2xl) {
  int idx = blockIdx.x * 256 + threadIdx.x;
  const int total = NN * 1536;
  for (; idx < total; idx += gridDim.x * 256) {
    int n = idx / 1536, r = idx - n * 1536;
    int ic = r / 3, j = r - ic * 3;
    int s2 = (n & 127) + j - 1;
    int b = n >> 7;
    float v = (s2 >= 0 && s2 < SS) ? h2c[(long)(b*SS + s2)*C2 + ic] : 0.f;
    uint bi = __float_as_uint(v);
    h2xh[idx] = (ushort)(bi >> 16);
    float rr = v - __uint_as_float(bi & 0xffff0000u);
    h2xl[idx] = (ushort)(__float_as_uint(rr) >> 16);
  }
}

// ---------------- S1: h3 = ew3 . h2x^T + eb3, 3xBF16 MFMA, no-LDS 1-wave blocks ----
// A = ew3 fp32 [7168][1536] (OTF split), B = h2x splits [256][1536]
// out: h3h/h3l bf16 [n=256][m=7168]
__global__ __launch_bounds__(64) void gemm_h3(const float* __restrict__ A,
    const ushort* __restrict__ Bh, const ushort* __restrict__ Bl,
    const float* __restrict__ eb3, ushort* __restrict__ h3h, ushort* __restrict__ h3l) {
  const int t = threadIdx.x;
  const int l15 = t & 15, quad = t >> 4;
  const int m0 = blockIdx.x * 64, n0 = blockIdx.y * 64;
  f32x4 acc[4][4] = {};
  const float*  aB = A  + (long)(m0 + l15) * 1536 + quad * 8;
  const ushort* bhB = Bh + (long)(n0 + l15) * 1536 + quad * 8;
  const ushort* blB = Bl + (long)(n0 + l15) * 1536 + quad * 8;
  for (int k0 = 0; k0 < 1536; k0 += 32) {
    short8 ah[4], al[4], bh[4], bl[4];
    #pragma unroll
    for (int f = 0; f < 4; ++f) {
      const float* ap = aB + (long)f * 16 * 1536 + k0;
      float4 x0 = *(const float4*)ap;
      float4 x1 = *(const float4*)(ap + 4);
      split8(x0, x1, ah[f], al[f]);
      bh[f] = *(const short8*)(bhB + (long)f * 16 * 1536 + k0);
      bl[f] = *(const short8*)(blB + (long)f * 16 * 1536 + k0);
    }
    #pragma unroll
    for (int i = 0; i < 4; ++i)
      #pragma unroll
      for (int j = 0; j < 4; ++j) {
        acc[i][j] = __builtin_amdgcn_mfma_f32_16x16x32_bf16(ah[i], bh[j], acc[i][j], 0, 0, 0);
        acc[i][j] = __builtin_amdgcn_mfma_f32_16x16x32_bf16(ah[i], bl[j], acc[i][j], 0, 0, 0);
        acc[i][j] = __builtin_amdgcn_mfma_f32_16x16x32_bf16(al[i], bh[j], acc[i][j], 0, 0, 0);
      }
  }
  #pragma unroll
  for (int i = 0; i < 4; ++i) {
    const int mbase = m0 + i * 16 + quad * 4;
    float4 bias = *(const float4*)(eb3 + mbase);
    #pragma unroll
    for (int j = 0; j < 4; ++j) {
      const int n = n0 + j * 16 + l15;
      float v0 = acc[i][j][0] + bias.x;
      float v1 = acc[i][j][1] + bias.y;
      float v2 = acc[i][j][2] + bias.z;
      float v3 = acc[i][j][3] + bias.w;
      uint b0 = __float_as_uint(v0), b1 = __float_as_uint(v1);
      uint b2 = __float_as_uint(v2), b3 = __float_as_uint(v3);
      uint2 hp;
      hp.x = (b0 >> 16) | (b1 & 0xffff0000u);
      hp.y = (b2 >> 16) | (b3 & 0xffff0000u);
      float r0 = v0 - __uint_as_float(b0 & 0xffff0000u);
      float r1 = v1 - __uint_as_float(b1 & 0xffff0000u);
      float r2 = v2 - __uint_as_float(b2 & 0xffff0000u);
      float r3 = v3 - __uint_as_float(b3 & 0xffff0000u);
      uint2 lp;
      lp.x = (__float_as_uint(r0) >> 16) | (__float_as_uint(r1) & 0xffff0000u);
      lp.y = (__float_as_uint(r2) >> 16) | (__float_as_uint(r3) & 0xffff0000u);
      long off = (long)n * C3 + mbase;
      *(uint2*)(h3h + off) = hp;
      *(uint2*)(h3l + off) = lp;
    }
  }
}

// ---------------- S2: scores = cbn - 2*cb.h3^T, 3xBF16 MFMA, no-LDS 1-wave blocks --
// A = cb fp32 [z][1024][512] (OTF split), B = h3 splits rows n, col offset z*512
__global__ __launch_bounds__(64) void gemm_scores(const float* __restrict__ cb,
    const ushort* __restrict__ h3h, const ushort* __restrict__ h3l,
    const float* __restrict__ cbn, float* __restrict__ scores) {
  const int t = threadIdx.x;
  const int l15 = t & 15, quad = t >> 4;
  const int m0 = blockIdx.x * 64, n0 = blockIdx.y * 64, z = blockIdx.z;
  f32x4 acc[4][4] = {};
  const float*  aB = cb + (long)z * VOC * DIMV + (long)(m0 + l15) * 512 + quad * 8;
  const ushort* bhB = h3h + (long)(n0 + l15) * C3 + z * 512 + quad * 8;
  const ushort* blB = h3l + (long)(n0 + l15) * C3 + z * 512 + quad * 8;
  for (int k0 = 0; k0 < 512; k0 += 32) {
    short8 ah[4], al[4], bh[4], bl[4];
    #pragma unroll
    for (int f = 0; f < 4; ++f) {
      const float* ap = aB + (long)f * 16 * 512 + k0;
      float4 x0 = *(const float4*)ap;
      float4 x1 = *(const float4*)(ap + 4);
      split8(x0, x1, ah[f], al[f]);
      bh[f] = *(const short8*)(bhB + (long)f * 16 * C3 + k0);
      bl[f] = *(const short8*)(blB + (long)f * 16 * C3 + k0);
    }
    #pragma unroll
    for (int i = 0; i < 4; ++i)
      #pragma unroll
      for (int j = 0; j < 4; ++j) {
        acc[i][j] = __builtin_amdgcn_mfma_f32_16x16x32_bf16(ah[i], bh[j], acc[i][j], 0, 0, 0);
        acc[i][j] = __builtin_amdgcn_mfma_f32_16x16x32_bf16(ah[i], bl[j], acc[i][j], 0, 0, 0);
        acc[i][j] = __builtin_amdgcn_mfma_f32_16x16x32_bf16(al[i], bh[j], acc[i][j], 0, 0, 0);
      }
  }
  #pragma unroll
  for (int i = 0; i < 4; ++i) {
    const int vbase = m0 + i * 16 + quad * 4;
    float4 cn = *(const float4*)(cbn + z * VOC + vbase);
    #pragma unroll
    for (int j = 0; j < 4; ++j) {
      const int n = n0 + j * 16 + l15;
      float4 out;
      out.x = cn.x - 2.f * acc[i][j][0];
      out.y = cn.y - 2.f * acc[i][j][1];
      out.z = cn.z - 2.f * acc[i][j][2];
      out.w = cn.w - 2.f * acc[i][j][3];
      *(float4*)(scores + ((long)z * NN + n) * VOC + vbase) = out;
    }
  }
}

// ---------------- argmin over 1024 codes, numpy tie-break (lowest v) ----------------
__global__ void k_argmin(const float* __restrict__ scores, int* __restrict__ codes) {
  int row = blockIdx.x;          // k*256+n
  int lane = threadIdx.x;        // 64
  const float* p = scores + (long)row * VOC;
  float best = 3.4e38f; int bi = 0;
  for (int i = 0; i < 16; ++i) {
    int v = i * 64 + lane;
    float x = p[v];
    if (x < best) { best = x; bi = v; }
  }
  for (int off = 32; off; off >>= 1) {
    float ob = __shfl_down(best, off);
    int oi = __shfl_down(bi, off);
    if (ob < best || (ob == best && oi < bi)) { best = ob; bi = oi; }
  }
  if (lane == 0) codes[row] = bi;
}

// ---------------- transpose+convert dw1 [7168][2560] fp32 -> dw1t [2560][7168] bf16 ----
__global__ __launch_bounds__(256) void k_dw1t(const float* __restrict__ dw1,
                                              ushort* __restrict__ dw1t) {
  __shared__ __align__(16) ushort T[64 * 72];   // [m][k] tile, pitch 72
  int t = threadIdx.x;
  int k0 = blockIdx.x * 64, m0 = blockIdx.y * 64;
  int kk = t >> 2, mj = (t & 3) * 16;
  const float* src = dw1 + (long)(k0 + kk) * 2560 + m0 + mj;
  float x[16];
  *(float4*)&x[0]  = *(const float4*)(src);
  *(float4*)&x[4]  = *(const float4*)(src + 4);
  *(float4*)&x[8]  = *(const float4*)(src + 8);
  *(float4*)&x[12] = *(const float4*)(src + 12);
  #pragma unroll
  for (int l = 0; l < 16; ++l)
    T[(mj + l) * 72 + kk] = f2bf(x[l]);
  __syncthreads();
  int mo = t >> 2, kc = (t & 3) * 16;
  uint4 u0 = *(const uint4*)&T[mo * 72 + kc];
  uint4 u1 = *(const uint4*)&T[mo * 72 + kc + 8];
  ushort* dst = dw1t + (long)(m0 + mo) * C3 + k0 + kc;
  *(uint4*)dst = u0;
  *(uint4*)(dst + 8) = u1;
}

// ---------------- gather q as bf16: qbf[n][k*512+d] = bf16(cb[k, code, d]) ----------
__global__ void k_gather_qbf(const float* __restrict__ cb, const int* __restrict__ codes,
                             ushort* __restrict__ qbf) {
  int idx = blockIdx.x * 256 + threadIdx.x;      // pair index
  const int total = NN * C3 / 2;                 // 917504
  if (idx >= total) return;
  int n = idx / 3584, rr = idx - n * 3584;       // rr = k*256 + dp
  int k = rr >> 8, dp = rr & 255;
  int code = codes[k * NN + n];
  const float* s = cb + ((long)(k * VOC + code)) * DIMV + dp * 2;
  uint lo = f2bf(s[0]), hi = f2bf(s[1]);
  ((uint*)qbf)[idx] = lo | (hi << 16);
}

// ---------------- decoder convT GEMM via MFMA bf16 ----------------
// a1raw[m=c*5+jj][n] = sum_k dw1t[m][k] * qbf[n][k];  64x64 tile, 4 waves 2x2 mfma
// LDS row stride 40 ushorts (80 B): frag reads land 2 lanes/bank-group (free)
__global__ __launch_bounds__(256) void gemm_a1_mfma(const ushort* __restrict__ dw1t,
    const ushort* __restrict__ qbf, float* __restrict__ a1raw) {
  __shared__ __align__(16) ushort As[64 * 40];
  __shared__ __align__(16) ushort Bs[64 * 40];
  const int tid = threadIdx.x;
  const int w = tid >> 6, lane = tid & 63;
  const int wm = w & 1, wn = w >> 1;
  const int m0 = blockIdx.x * 64, n0 = blockIdx.y * 64;
  const int l15 = lane & 15, quad = lane >> 4;
  const int r = tid >> 2, koff = (tid & 3) * 8;
  const ushort* aP = dw1t + (long)(m0 + r) * C3 + koff;
  const ushort* bP = qbf + (long)(n0 + r) * C3 + koff;
  f32x4 acc[2][2] = {};
  const int aoff0 = (wm * 32 + l15) * 40 + quad * 8;
  const int aoff1 = (wm * 32 + 16 + l15) * 40 + quad * 8;
  const int boff0 = (wn * 32 + l15) * 40 + quad * 8;
  const int boff1 = (wn * 32 + 16 + l15) * 40 + quad * 8;
  const int soff = r * 40 + koff;
  for (int k0 = 0; k0 < C3; k0 += 32) {
    uint4 av = *(const uint4*)(aP + k0);
    uint4 bv = *(const uint4*)(bP + k0);
    *(uint4*)&As[soff] = av;
    *(uint4*)&Bs[soff] = bv;
    __syncthreads();
    short8 a0 = *(const short8*)&As[aoff0];
    short8 a1 = *(const short8*)&As[aoff1];
    short8 b0 = *(const short8*)&Bs[boff0];
    short8 b1 = *(const short8*)&Bs[boff1];
    acc[0][0] = __builtin_amdgcn_mfma_f32_16x16x32_bf16(a0, b0, acc[0][0], 0, 0, 0);
    acc[0][1] = __builtin_amdgcn_mfma_f32_16x16x32_bf16(a0, b1, acc[0][1], 0, 0, 0);
    acc[1][0] = __builtin_amdgcn_mfma_f32_16x16x32_bf16(a1, b0, acc[1][0], 0, 0, 0);
    acc[1][1] = __builtin_amdgcn_mfma_f32_16x16x32_bf16(a1, b1, acc[1][1], 0, 0, 0);
    __syncthreads();
  }
  #pragma unroll
  for (int i = 0; i < 2; ++i)
    #pragma unroll
    for (int j = 0; j < 2; ++j)
      #pragma unroll
      for (int reg = 0; reg < 4; ++reg) {
        int m = m0 + wm * 32 + i * 16 + quad * 4 + reg;
        int n = n0 + wn * 32 + j * 16 + l15;
        int c = m / 5, jj = m - c * 5;
        a1raw[((long)(n * 5 + jj)) * C2 + c] = acc[i][j][reg];
      }
}

// ---------------- decoder conv2 on the 9 active cols per (b,s) ----------------
__global__ __launch_bounds__(256) void k_dec2(const float* __restrict__ a1raw,
    const float* __restrict__ ab1g, const float* __restrict__ db1,
    const float* __restrict__ dw2, const float* __restrict__ db2,
    float* __restrict__ a2act) {
  __shared__ float P[C2][20];
  int n = blockIdx.x;
  int s = n & 127;
  int t = threadIdx.x;
  for (int i = t; i < 13 * C2; i += 256) {
    int w = i / C2, c = i - w * C2;
    int tc = HOP * s - 6 + w;
    float v;
    if (tc < 0 || tc > TOUT - 1) v = 0.f;
    else {
      int dj = tc - HOP * s + 2;
      if (dj >= 0 && dj <= 4)
        v = fmaxf(db1[c] + a1raw[((long)(n * 5 + dj)) * C2 + c], 0.f);
      else v = ab1g[c];
    }
    P[c][w] = v;
  }
  __syncthreads();
  int o = t;
  float acc[9];
  float bias = db2[o];
  #pragma unroll
  for (int u = 0; u < 9; ++u) acc[u] = bias;
  const float* wp = dw2 + (long)o * C2 * 5;
  for (int c = 0; c < C2; ++c) {
    float p[13];
    float4 p0 = *(const float4*)&P[c][0];
    float4 p1 = *(const float4*)&P[c][4];
    float4 p2 = *(const float4*)&P[c][8];
    p[0]=p0.x; p[1]=p0.y; p[2]=p0.z; p[3]=p0.w;
    p[4]=p1.x; p[5]=p1.y; p[6]=p1.z; p[7]=p1.w;
    p[8]=p2.x; p[9]=p2.y; p[10]=p2.z; p[11]=p2.w;
    p[12]=P[c][12];
    #pragma unroll
    for (int jj = 0; jj < 5; ++jj) {
      float w = wp[c*5+jj];
      #pragma unroll
      for (int u = 0; u < 9; ++u) acc[u] = fmaf(w, p[u + jj], acc[u]);
    }
  }
  #pragma unroll
  for (int u = 0; u < 9; ++u)
    a2act[((long)(n * 9 + u)) * C1 + o] = fmaxf(acc[u], 0.f);
}

// ---------------- fill output with the constant tanh value ----------------
__global__ void k_fill(float* __restrict__ outp, const float* __restrict__ cconst) {
  float v = cconst[0];
  int idx = blockIdx.x * 256 + threadIdx.x;
  const int total = NBATCH * TOUT;
  for (; idx < total; idx += gridDim.x * 256) outp[idx] = v;
}

// ---------------- decoder conv3+tanh on 15 active cols per (b,s) ----------------
__global__ __launch_bounds__(256) void k_dec3(const float* __restrict__ a2act,
    const float* __restrict__ ab2g, const float* __restrict__ dw3,
    const float* __restrict__ db3, float* __restrict__ outp) {
  __shared__ float sa2[9 * C1];
  __shared__ float sb[C1];
  int n = blockIdx.x;
  int s = n & 127, b = n >> 7;
  int t = threadIdx.x;
  for (int i = t; i < 9 * C1; i += 256) sa2[i] = a2act[(long)n * 9 * C1 + i];
  sb[t] = ab2g[t];
  __syncthreads();
  int wv = t >> 6, lane = t & 63;
  float b3 = db3[0];
  for (int w15 = wv; w15 < 15; w15 += 4) {
    int tc = HOP * s - 7 + w15;
    if (tc < 0 || tc > TOUT - 1) continue;
    float part = 0.f;
    for (int cc = lane; cc < C1; cc += 64) {
      #pragma unroll
      for (int j = 0; j < 7; ++j) {
        int wcol = tc + j - 3;
        float x;
        if (wcol < 0 || wcol > TOUT - 1) x = 0.f;
        else {
          int du = wcol - (HOP * s - 4);
          x = (du >= 0 && du <= 8) ? sa2[du * C1 + cc] : sb[cc];
        }
        part = fmaf(dw3[cc*7+j], x, part);
      }
    }
    for (int off = 32; off; off >>= 1) part += __shfl_down(part, off);
    if (lane == 0) outp[(long)b * TOUT + tc] = tanhf(part + b3);
  }
}

extern "C" void kernel_launch(void* const* d_in, const int* in_sizes, int n_in,
                              void* d_out, int out_size, void* d_ws, size_t ws_size,
                              hipStream_t stream) {
  const float* audio = (const float*)d_in[0];
  const float* cb    = (const float*)d_in[1];
  const float* ew1   = (const float*)d_in[2];
  const float* eb1   = (const float*)d_in[3];
  const float* ew2   = (const float*)d_in[4];
  const float* eb2   = (const float*)d_in[5];
  const float* ew3   = (const float*)d_in[6];
  const float* eb3   = (const float*)d_in[7];
  const float* dw1   = (const float*)d_in[8];
  const float* db1   = (const float*)d_in[9];
  const float* dw2   = (const float*)d_in[10];
  const float* db2   = (const float*)d_in[11];
  const float* dw3   = (const float*)d_in[12];
  const float* db3   = (const float*)d_in[13];
  float* outp = (float*)d_out;
  float* ws = (float*)d_ws;

  float*  cbn    = ws + OFF_CBN;
  float*  ab1    = ws + OFF_AB1;
  float*  ab2    = ws + OFF_AB2;
  float*  cconst = ws + OFF_CCONST;
  float*  h2c    = ws + OFF_H2C;
  ushort* h2xh   = (ushort*)(ws + OFF_H2XH);
  ushort* h2xl   = (ushort*)(ws + OFF_H2XL);
  ushort* h3h    = (ushort*)(ws + OFF_H3H);
  ushort* h3l    = (ushort*)(ws + OFF_H3L);
  float*  scores = ws + OFF_SCORES;
  ushort* dw1t   = (ushort*)(ws + OFF_DW1T);
  int*    codes  = (int*)(ws + OFF_CODES);
  ushort* qbf    = (ushort*)(ws + OFF_QBF);
  float*  a1raw  = ws + OFF_A1RAW;
  float*  a2act  = ws + OFF_A2ACT;

  k_cbn<<<3584, 256, 0, stream>>>(cb, cbn);
  k_prep<<<1, 256, 0, stream>>>(db1, dw2, db2, dw3, db3, ab1, ab2, cconst);
  k_enc12<<<SS, 256, 0, stream>>>(audio, ew1, eb1, ew2, eb2, h2c);
  k_h2x<<<384, 256, 0, stream>>>(h2c, h2xh, h2xl);
  gemm_h3<<<dim3(112, 4), 64, 0, stream>>>(ew3, h2xh, h2xl, eb3, h3h, h3l);
  gemm_scores<<<dim3(16, 4, 14), 64, 0, stream>>>(cb, h3h, h3l, cbn, scores);
  k_argmin<<<NCBK * NN, 64, 0, stream>>>(scores, codes);
  // dw1t overlaps h3h/h3l/scores memory: must launch AFTER k_argmin (stream-ordered)
  k_dw1t<<<dim3(112, 40), 256, 0, stream>>>(dw1, dw1t);
  k_gather_qbf<<<3584, 256, 0, stream>>>(cb, codes, qbf);
  gemm_a1_mfma<<<dim3(40, 4), 256, 0, stream>>>(dw1t, qbf, a1raw);
  k_dec2<<<NN, 256, 0, stream>>>(a1raw, ab1, db1, dw2, db2, a2act);
  k_fill<<<256, 256, 0, stream>>>(outp, cconst);
  k_dec3<<<NN, 256, 0, stream>>>(a2act, ab2, dw3, db3, outp);
}

// Round 4
// 633.935 us; speedup vs baseline: 1.3913x; 1.2004x over previous
//
#include <hip/hip_runtime.h>
#include <hip/hip_bf16.h>
#include <math.h>

#define T_IN 98304
#define SS 128
#define NBATCH 2
#define NN 256          // NBATCH*SS
#define C1 256
#define C2 512
#define C3 7168
#define NCBK 14
#define DIMV 512
#define VOC 1024
#define TOUT 97537
#define HOP 768

// ws layout (float offsets)
#define OFF_CBN    0L          // 14336
#define OFF_AB1    14336L      // 512
#define OFF_AB2    14848L      // 256
#define OFF_CCONST 15104L      // 16
#define OFF_H2C    15120L      // 131072   (n*512+ic), n=b*128+s
#define OFF_H2XH   146192L     // 196608 fl (ushort [256][1536] bf16-hi)
#define OFF_H2XL   342800L     // 196608 fl (bf16-lo)
#define OFF_H3H    539408L     // 917504 fl (ushort [256][7168] bf16-hi)
#define OFF_H3L    1456912L    // 917504 fl
#define OFF_SCORES 2374416L    // 3670016  ((k*256+n)*1024 + v)
// dw1t (bf16 [2560][7168] = 9175040 fl) OVERLAPS h3h/h3l/scores: all dead
// before k_dw1t runs (launched after k_argmin; same stream serializes).
#define OFF_DW1T   539408L     // ends 9714448
#define OFF_CODES  9714448L    // 3584 ints
#define OFF_QBF    9718032L    // 917504 fl (bf16 [256][7168])
#define OFF_A1RAW  10635536L   // 655360   ((n*5+j)*512 + c)  pre-bias/relu
#define OFF_A2ACT  11290896L   // 589824   ((n*9+u)*256 + o)  post-relu
// total 11880720 floats = 47.5 MB

typedef __attribute__((ext_vector_type(8))) short short8;
typedef __attribute__((ext_vector_type(4))) float f32x4;

static __device__ inline ushort f2bf(float x) {
  __hip_bfloat16 h = __float2bfloat16(x);
  return *reinterpret_cast<ushort*>(&h);
}

// exact 2-term split: x = hi + lo + O(2^-16 |x|); truncation split, residual exact
static __device__ inline void split8(const float4 x0, const float4 x1,
                                     short8& h, short8& l) {
  float xs[8] = {x0.x, x0.y, x0.z, x0.w, x1.x, x1.y, x1.z, x1.w};
  #pragma unroll
  for (int e = 0; e < 8; ++e) {
    uint b = __float_as_uint(xs[e]);
    h[e] = (short)(b >> 16);
    float r = xs[e] - __uint_as_float(b & 0xffff0000u);
    l[e] = (short)(__float_as_uint(r) >> 16);
  }
}

// ---------------- prep: codebook norms ----------------
__global__ void k_cbn(const float* __restrict__ cb, float* __restrict__ cbn) {
  int row = blockIdx.x * 4 + (threadIdx.x >> 6);
  int lane = threadIdx.x & 63;
  const float* p = cb + (long)row * DIMV;
  float s = 0.f;
  for (int d = lane; d < DIMV; d += 64) { float x = p[d]; s += x * x; }
  for (int off = 32; off; off >>= 1) s += __shfl_down(s, off);
  if (lane == 0) cbn[row] = s;
}

// ---------------- prep A: ab1 = relu(db1); ab2[o] = relu(db2[o]+sum_c W(o,c)*ab1[c])
// one block per o; block reads its contiguous 10 KB dw2 row, LDS-reduces over c
__global__ __launch_bounds__(256) void k_prep_ab2(const float* __restrict__ db1,
    const float* __restrict__ dw2, const float* __restrict__ db2,
    float* __restrict__ ab1, float* __restrict__ ab2) {
  __shared__ float red[256];
  int o = blockIdx.x, t = threadIdx.x;
  if (o == 0) { ab1[t] = fmaxf(db1[t], 0.f); ab1[t + 256] = fmaxf(db1[t + 256], 0.f); }
  const float* wp = dw2 + (long)o * C2 * 5;
  float acc = 0.f;
  #pragma unroll
  for (int h = 0; h < 2; ++h) {
    int c = t + h * 256;
    const float* p = wp + c * 5;
    float wsum = p[0] + p[1] + p[2] + p[3] + p[4];
    acc = fmaf(wsum, fmaxf(db1[c], 0.f), acc);
  }
  red[t] = acc;
  __syncthreads();
  for (int off = 128; off; off >>= 1) {
    if (t < off) red[t] += red[t + off];
    __syncthreads();
  }
  if (t == 0) ab2[o] = fmaxf(red[0] + db2[o], 0.f);
}

// ---------------- prep B: cconst = tanh(db3 + sum_o (sum_j dw3[o][j]) * ab2[o]) ----
__global__ __launch_bounds__(256) void k_prep_c(const float* __restrict__ dw3,
    const float* __restrict__ db3, const float* __restrict__ ab2,
    float* __restrict__ cconst) {
  __shared__ float red[256];
  int t = threadIdx.x;
  float wsum3 = 0.f;
  #pragma unroll
  for (int j = 0; j < 7; ++j) wsum3 += dw3[t*7+j];
  red[t] = wsum3 * ab2[t];
  __syncthreads();
  for (int off = 128; off; off >>= 1) {
    if (t < off) red[t] += red[t + off];
    __syncthreads();
  }
  if (t == 0) cconst[0] = tanhf(red[0] + db3[0]);
}

// ---------------- fused encoder conv1 (k7,p3) + conv2 (k5,s768,p2) ----------------
__global__ __launch_bounds__(256) void k_enc12(const float* __restrict__ audio,
    const float* __restrict__ ew1, const float* __restrict__ eb1,
    const float* __restrict__ ew2, const float* __restrict__ eb2,
    float* __restrict__ h2c) {
  __shared__ float h1s[NBATCH][5][C1];
  int s = blockIdx.x;
  int ic = threadIdx.x;
  float w1[7];
  #pragma unroll
  for (int j = 0; j < 7; ++j) w1[j] = ew1[ic*7+j];
  float b1 = eb1[ic];
  for (int b = 0; b < NBATCH; ++b) {
    const float* ap = audio + (long)b * T_IN;
    #pragma unroll
    for (int jj = 0; jj < 5; ++jj) {
      int tcol = HOP * s + jj - 2;
      float v = 0.f;
      if (tcol >= 0) {
        float acc = b1;
        #pragma unroll
        for (int j = 0; j < 7; ++j) {
          int ai = tcol + j - 3;
          float a = (ai >= 0 && ai < T_IN) ? ap[ai] : 0.f;
          acc = fmaf(w1[j], a, acc);
        }
        v = fmaxf(acc, 0.f);
      }
      h1s[b][jj][ic] = v;
    }
  }
  __syncthreads();
  for (int oo = 0; oo < 2; ++oo) {
    int oc = threadIdx.x + oo * 256;
    float acc0 = eb2[oc], acc1 = acc0;
    const float* wp = ew2 + (long)oc * C1 * 5;
    for (int icc = 0; icc < C1; ++icc) {
      #pragma unroll
      for (int jj = 0; jj < 5; ++jj) {
        float w = wp[icc*5+jj];
        acc0 = fmaf(w, h1s[0][jj][icc], acc0);
        acc1 = fmaf(w, h1s[1][jj][icc], acc1);
      }
    }
    h2c[(long)(0*SS + s)*C2 + oc] = fmaxf(acc0, 0.f);
    h2c[(long)(1*SS + s)*C2 + oc] = fmaxf(acc1, 0.f);
  }
}

// ---------------- im2col for conv3 (k3,p1), written as bf16 hi/lo split ----------
__global__ void k_h2x(const float* __restrict__ h2c, ushort* __restrict__ h2xh,
                      ushort* __restrict__ h2xl) {
  int idx = blockIdx.x * 256 + threadIdx.x;
  const int total = NN * 1536;
  for (; idx < total; idx += gridDim.x * 256) {
    int n = idx / 1536, r = idx - n * 1536;
    int ic = r / 3, j = r - ic * 3;
    int s2 = (n & 127) + j - 1;
    int b = n >> 7;
    float v = (s2 >= 0 && s2 < SS) ? h2c[(long)(b*SS + s2)*C2 + ic] : 0.f;
    uint bi = __float_as_uint(v);
    h2xh[idx] = (ushort)(bi >> 16);
    float rr = v - __uint_as_float(bi & 0xffff0000u);
    h2xl[idx] = (ushort)(__float_as_uint(rr) >> 16);
  }
}

// ---------------- S1: h3 = ew3 . h2x^T + eb3, 3xBF16 MFMA, no-LDS 1-wave blocks ----
__global__ __launch_bounds__(64) void gemm_h3(const float* __restrict__ A,
    const ushort* __restrict__ Bh, const ushort* __restrict__ Bl,
    const float* __restrict__ eb3, ushort* __restrict__ h3h, ushort* __restrict__ h3l) {
  const int t = threadIdx.x;
  const int l15 = t & 15, quad = t >> 4;
  const int m0 = blockIdx.x * 64, n0 = blockIdx.y * 64;
  f32x4 acc[4][4] = {};
  const float*  aB = A  + (long)(m0 + l15) * 1536 + quad * 8;
  const ushort* bhB = Bh + (long)(n0 + l15) * 1536 + quad * 8;
  const ushort* blB = Bl + (long)(n0 + l15) * 1536 + quad * 8;
  for (int k0 = 0; k0 < 1536; k0 += 32) {
    short8 ah[4], al[4], bh[4], bl[4];
    #pragma unroll
    for (int f = 0; f < 4; ++f) {
      const float* ap = aB + (long)f * 16 * 1536 + k0;
      float4 x0 = *(const float4*)ap;
      float4 x1 = *(const float4*)(ap + 4);
      split8(x0, x1, ah[f], al[f]);
      bh[f] = *(const short8*)(bhB + (long)f * 16 * 1536 + k0);
      bl[f] = *(const short8*)(blB + (long)f * 16 * 1536 + k0);
    }
    #pragma unroll
    for (int i = 0; i < 4; ++i)
      #pragma unroll
      for (int j = 0; j < 4; ++j) {
        acc[i][j] = __builtin_amdgcn_mfma_f32_16x16x32_bf16(ah[i], bh[j], acc[i][j], 0, 0, 0);
        acc[i][j] = __builtin_amdgcn_mfma_f32_16x16x32_bf16(ah[i], bl[j], acc[i][j], 0, 0, 0);
        acc[i][j] = __builtin_amdgcn_mfma_f32_16x16x32_bf16(al[i], bh[j], acc[i][j], 0, 0, 0);
      }
  }
  #pragma unroll
  for (int i = 0; i < 4; ++i) {
    const int mbase = m0 + i * 16 + quad * 4;
    float4 bias = *(const float4*)(eb3 + mbase);
    #pragma unroll
    for (int j = 0; j < 4; ++j) {
      const int n = n0 + j * 16 + l15;
      float v0 = acc[i][j][0] + bias.x;
      float v1 = acc[i][j][1] + bias.y;
      float v2 = acc[i][j][2] + bias.z;
      float v3 = acc[i][j][3] + bias.w;
      uint b0 = __float_as_uint(v0), b1 = __float_as_uint(v1);
      uint b2 = __float_as_uint(v2), b3 = __float_as_uint(v3);
      uint2 hp;
      hp.x = (b0 >> 16) | (b1 & 0xffff0000u);
      hp.y = (b2 >> 16) | (b3 & 0xffff0000u);
      float r0 = v0 - __uint_as_float(b0 & 0xffff0000u);
      float r1 = v1 - __uint_as_float(b1 & 0xffff0000u);
      float r2 = v2 - __uint_as_float(b2 & 0xffff0000u);
      float r3 = v3 - __uint_as_float(b3 & 0xffff0000u);
      uint2 lp;
      lp.x = (__float_as_uint(r0) >> 16) | (__float_as_uint(r1) & 0xffff0000u);
      lp.y = (__float_as_uint(r2) >> 16) | (__float_as_uint(r3) & 0xffff0000u);
      long off = (long)n * C3 + mbase;
      *(uint2*)(h3h + off) = hp;
      *(uint2*)(h3l + off) = lp;
    }
  }
}

// ---------------- S2: scores = cbn - 2*cb.h3^T, 3xBF16 MFMA, no-LDS 1-wave blocks --
__global__ __launch_bounds__(64) void gemm_scores(const float* __restrict__ cb,
    const ushort* __restrict__ h3h, const ushort* __restrict__ h3l,
    const float* __restrict__ cbn, float* __restrict__ scores) {
  const int t = threadIdx.x;
  const int l15 = t & 15, quad = t >> 4;
  const int m0 = blockIdx.x * 64, n0 = blockIdx.y * 64, z = blockIdx.z;
  f32x4 acc[4][4] = {};
  const float*  aB = cb + (long)z * VOC * DIMV + (long)(m0 + l15) * 512 + quad * 8;
  const ushort* bhB = h3h + (long)(n0 + l15) * C3 + z * 512 + quad * 8;
  const ushort* blB = h3l + (long)(n0 + l15) * C3 + z * 512 + quad * 8;
  for (int k0 = 0; k0 < 512; k0 += 32) {
    short8 ah[4], al[4], bh[4], bl[4];
    #pragma unroll
    for (int f = 0; f < 4; ++f) {
      const float* ap = aB + (long)f * 16 * 512 + k0;
      float4 x0 = *(const float4*)ap;
      float4 x1 = *(const float4*)(ap + 4);
      split8(x0, x1, ah[f], al[f]);
      bh[f] = *(const short8*)(bhB + (long)f * 16 * C3 + k0);
      bl[f] = *(const short8*)(blB + (long)f * 16 * C3 + k0);
    }
    #pragma unroll
    for (int i = 0; i < 4; ++i)
      #pragma unroll
      for (int j = 0; j < 4; ++j) {
        acc[i][j] = __builtin_amdgcn_mfma_f32_16x16x32_bf16(ah[i], bh[j], acc[i][j], 0, 0, 0);
        acc[i][j] = __builtin_amdgcn_mfma_f32_16x16x32_bf16(ah[i], bl[j], acc[i][j], 0, 0, 0);
        acc[i][j] = __builtin_amdgcn_mfma_f32_16x16x32_bf16(al[i], bh[j], acc[i][j], 0, 0, 0);
      }
  }
  #pragma unroll
  for (int i = 0; i < 4; ++i) {
    const int vbase = m0 + i * 16 + quad * 4;
    float4 cn = *(const float4*)(cbn + z * VOC + vbase);
    #pragma unroll
    for (int j = 0; j < 4; ++j) {
      const int n = n0 + j * 16 + l15;
      float4 out;
      out.x = cn.x - 2.f * acc[i][j][0];
      out.y = cn.y - 2.f * acc[i][j][1];
      out.z = cn.z - 2.f * acc[i][j][2];
      out.w = cn.w - 2.f * acc[i][j][3];
      *(float4*)(scores + ((long)z * NN + n) * VOC + vbase) = out;
    }
  }
}

// ---------------- argmin over 1024 codes, numpy tie-break (lowest v) ----------------
__global__ void k_argmin(const float* __restrict__ scores, int* __restrict__ codes) {
  int row = blockIdx.x;          // k*256+n
  int lane = threadIdx.x;        // 64
  const float* p = scores + (long)row * VOC;
  float best = 3.4e38f; int bi = 0;
  for (int i = 0; i < 16; ++i) {
    int v = i * 64 + lane;
    float x = p[v];
    if (x < best) { best = x; bi = v; }
  }
  for (int off = 32; off; off >>= 1) {
    float ob = __shfl_down(best, off);
    int oi = __shfl_down(bi, off);
    if (ob < best || (ob == best && oi < bi)) { best = ob; bi = oi; }
  }
  if (lane == 0) codes[row] = bi;
}

// ---------------- transpose+convert dw1 [7168][2560] fp32 -> dw1t [2560][7168] bf16 ----
__global__ __launch_bounds__(256) void k_dw1t(const float* __restrict__ dw1,
                                              ushort* __restrict__ dw1t) {
  __shared__ __align__(16) ushort T[64 * 72];   // [m][k] tile, pitch 72
  int t = threadIdx.x;
  int k0 = blockIdx.x * 64, m0 = blockIdx.y * 64;
  int kk = t >> 2, mj = (t & 3) * 16;
  const float* src = dw1 + (long)(k0 + kk) * 2560 + m0 + mj;
  float x[16];
  *(float4*)&x[0]  = *(const float4*)(src);
  *(float4*)&x[4]  = *(const float4*)(src + 4);
  *(float4*)&x[8]  = *(const float4*)(src + 8);
  *(float4*)&x[12] = *(const float4*)(src + 12);
  #pragma unroll
  for (int l = 0; l < 16; ++l)
    T[(mj + l) * 72 + kk] = f2bf(x[l]);
  __syncthreads();
  int mo = t >> 2, kc = (t & 3) * 16;
  uint4 u0 = *(const uint4*)&T[mo * 72 + kc];
  uint4 u1 = *(const uint4*)&T[mo * 72 + kc + 8];
  ushort* dst = dw1t + (long)(m0 + mo) * C3 + k0 + kc;
  *(uint4*)dst = u0;
  *(uint4*)(dst + 8) = u1;
}

// ---------------- gather q as bf16: qbf[n][k*512+d] = bf16(cb[k, code, d]) ----------
__global__ void k_gather_qbf(const float* __restrict__ cb, const int* __restrict__ codes,
                             ushort* __restrict__ qbf) {
  int idx = blockIdx.x * 256 + threadIdx.x;      // pair index
  const int total = NN * C3 / 2;                 // 917504
  if (idx >= total) return;
  int n = idx / 3584, rr = idx - n * 3584;       // rr = k*256 + dp
  int k = rr >> 8, dp = rr & 255;
  int code = codes[k * NN + n];
  const float* s = cb + ((long)(k * VOC + code)) * DIMV + dp * 2;
  uint lo = f2bf(s[0]), hi = f2bf(s[1]);
  ((uint*)qbf)[idx] = lo | (hi << 16);
}

// ---------------- decoder convT GEMM via MFMA bf16 ----------------
__global__ __launch_bounds__(256) void gemm_a1_mfma(const ushort* __restrict__ dw1t,
    const ushort* __restrict__ qbf, float* __restrict__ a1raw) {
  __shared__ __align__(16) ushort As[64 * 40];
  __shared__ __align__(16) ushort Bs[64 * 40];
  const int tid = threadIdx.x;
  const int w = tid >> 6, lane = tid & 63;
  const int wm = w & 1, wn = w >> 1;
  const int m0 = blockIdx.x * 64, n0 = blockIdx.y * 64;
  const int l15 = lane & 15, quad = lane >> 4;
  const int r = tid >> 2, koff = (tid & 3) * 8;
  const ushort* aP = dw1t + (long)(m0 + r) * C3 + koff;
  const ushort* bP = qbf + (long)(n0 + r) * C3 + koff;
  f32x4 acc[2][2] = {};
  const int aoff0 = (wm * 32 + l15) * 40 + quad * 8;
  const int aoff1 = (wm * 32 + 16 + l15) * 40 + quad * 8;
  const int boff0 = (wn * 32 + l15) * 40 + quad * 8;
  const int boff1 = (wn * 32 + 16 + l15) * 40 + quad * 8;
  const int soff = r * 40 + koff;
  for (int k0 = 0; k0 < C3; k0 += 32) {
    uint4 av = *(const uint4*)(aP + k0);
    uint4 bv = *(const uint4*)(bP + k0);
    *(uint4*)&As[soff] = av;
    *(uint4*)&Bs[soff] = bv;
    __syncthreads();
    short8 a0 = *(const short8*)&As[aoff0];
    short8 a1 = *(const short8*)&As[aoff1];
    short8 b0 = *(const short8*)&Bs[boff0];
    short8 b1 = *(const short8*)&Bs[boff1];
    acc[0][0] = __builtin_amdgcn_mfma_f32_16x16x32_bf16(a0, b0, acc[0][0], 0, 0, 0);
    acc[0][1] = __builtin_amdgcn_mfma_f32_16x16x32_bf16(a0, b1, acc[0][1], 0, 0, 0);
    acc[1][0] = __builtin_amdgcn_mfma_f32_16x16x32_bf16(a1, b0, acc[1][0], 0, 0, 0);
    acc[1][1] = __builtin_amdgcn_mfma_f32_16x16x32_bf16(a1, b1, acc[1][1], 0, 0, 0);
    __syncthreads();
  }
  #pragma unroll
  for (int i = 0; i < 2; ++i)
    #pragma unroll
    for (int j = 0; j < 2; ++j)
      #pragma unroll
      for (int reg = 0; reg < 4; ++reg) {
        int m = m0 + wm * 32 + i * 16 + quad * 4 + reg;
        int n = n0 + wn * 32 + j * 16 + l15;
        int c = m / 5, jj = m - c * 5;
        a1raw[((long)(n * 5 + jj)) * C2 + c] = acc[i][j][reg];
      }
}

// ---------------- decoder conv2 on the 9 active cols per (b,s) ----------------
__global__ __launch_bounds__(256) void k_dec2(const float* __restrict__ a1raw,
    const float* __restrict__ ab1g, const float* __restrict__ db1,
    const float* __restrict__ dw2, const float* __restrict__ db2,
    float* __restrict__ a2act) {
  __shared__ float P[C2][20];
  int n = blockIdx.x;
  int s = n & 127;
  int t = threadIdx.x;
  for (int i = t; i < 13 * C2; i += 256) {
    int w = i / C2, c = i - w * C2;
    int tc = HOP * s - 6 + w;
    float v;
    if (tc < 0 || tc > TOUT - 1) v = 0.f;
    else {
      int dj = tc - HOP * s + 2;
      if (dj >= 0 && dj <= 4)
        v = fmaxf(db1[c] + a1raw[((long)(n * 5 + dj)) * C2 + c], 0.f);
      else v = ab1g[c];
    }
    P[c][w] = v;
  }
  __syncthreads();
  int o = t;
  float acc[9];
  float bias = db2[o];
  #pragma unroll
  for (int u = 0; u < 9; ++u) acc[u] = bias;
  const float* wp = dw2 + (long)o * C2 * 5;
  for (int c = 0; c < C2; ++c) {
    float p[13];
    float4 p0 = *(const float4*)&P[c][0];
    float4 p1 = *(const float4*)&P[c][4];
    float4 p2 = *(const float4*)&P[c][8];
    p[0]=p0.x; p[1]=p0.y; p[2]=p0.z; p[3]=p0.w;
    p[4]=p1.x; p[5]=p1.y; p[6]=p1.z; p[7]=p1.w;
    p[8]=p2.x; p[9]=p2.y; p[10]=p2.z; p[11]=p2.w;
    p[12]=P[c][12];
    #pragma unroll
    for (int jj = 0; jj < 5; ++jj) {
      float w = wp[c*5+jj];
      #pragma unroll
      for (int u = 0; u < 9; ++u) acc[u] = fmaf(w, p[u + jj], acc[u]);
    }
  }
  #pragma unroll
  for (int u = 0; u < 9; ++u)
    a2act[((long)(n * 9 + u)) * C1 + o] = fmaxf(acc[u], 0.f);
}

// ---------------- fill output with the constant tanh value ----------------
__global__ void k_fill(float* __restrict__ outp, const float* __restrict__ cconst) {
  float v = cconst[0];
  int idx = blockIdx.x * 256 + threadIdx.x;
  const int total = NBATCH * TOUT;
  for (; idx < total; idx += gridDim.x * 256) outp[idx] = v;
}

// ---------------- decoder conv3+tanh on 15 active cols per (b,s) ----------------
__global__ __launch_bounds__(256) void k_dec3(const float* __restrict__ a2act,
    const float* __restrict__ ab2g, const float* __restrict__ dw3,
    const float* __restrict__ db3, float* __restrict__ outp) {
  __shared__ float sa2[9 * C1];
  __shared__ float sb[C1];
  int n = blockIdx.x;
  int s = n & 127, b = n >> 7;
  int t = threadIdx.x;
  for (int i = t; i < 9 * C1; i += 256) sa2[i] = a2act[(long)n * 9 * C1 + i];
  sb[t] = ab2g[t];
  __syncthreads();
  int wv = t >> 6, lane = t & 63;
  float b3 = db3[0];
  for (int w15 = wv; w15 < 15; w15 += 4) {
    int tc = HOP * s - 7 + w15;
    if (tc < 0 || tc > TOUT - 1) continue;
    float part = 0.f;
    for (int cc = lane; cc < C1; cc += 64) {
      #pragma unroll
      for (int j = 0; j < 7; ++j) {
        int wcol = tc + j - 3;
        float x;
        if (wcol < 0 || wcol > TOUT - 1) x = 0.f;
        else {
          int du = wcol - (HOP * s - 4);
          x = (du >= 0 && du <= 8) ? sa2[du * C1 + cc] : sb[cc];
        }
        part = fmaf(dw3[cc*7+j], x, part);
      }
    }
    for (int off = 32; off; off >>= 1) part += __shfl_down(part, off);
    if (lane == 0) outp[(long)b * TOUT + tc] = tanhf(part + b3);
  }
}

extern "C" void kernel_launch(void* const* d_in, const int* in_sizes, int n_in,
                              void* d_out, int out_size, void* d_ws, size_t ws_size,
                              hipStream_t stream) {
  const float* audio = (const float*)d_in[0];
  const float* cb    = (const float*)d_in[1];
  const float* ew1   = (const float*)d_in[2];
  const float* eb1   = (const float*)d_in[3];
  const float* ew2   = (const float*)d_in[4];
  const float* eb2   = (const float*)d_in[5];
  const float* ew3   = (const float*)d_in[6];
  const float* eb3   = (const float*)d_in[7];
  const float* dw1   = (const float*)d_in[8];
  const float* db1   = (const float*)d_in[9];
  const float* dw2   = (const float*)d_in[10];
  const float* db2   = (const float*)d_in[11];
  const float* dw3   = (const float*)d_in[12];
  const float* db3   = (const float*)d_in[13];
  float* outp = (float*)d_out;
  float* ws = (float*)d_ws;

  float*  cbn    = ws + OFF_CBN;
  float*  ab1    = ws + OFF_AB1;
  float*  ab2    = ws + OFF_AB2;
  float*  cconst = ws + OFF_CCONST;
  float*  h2c    = ws + OFF_H2C;
  ushort* h2xh   = (ushort*)(ws + OFF_H2XH);
  ushort* h2xl   = (ushort*)(ws + OFF_H2XL);
  ushort* h3h    = (ushort*)(ws + OFF_H3H);
  ushort* h3l    = (ushort*)(ws + OFF_H3L);
  float*  scores = ws + OFF_SCORES;
  ushort* dw1t   = (ushort*)(ws + OFF_DW1T);
  int*    codes  = (int*)(ws + OFF_CODES);
  ushort* qbf    = (ushort*)(ws + OFF_QBF);
  float*  a1raw  = ws + OFF_A1RAW;
  float*  a2act  = ws + OFF_A2ACT;

  k_cbn<<<3584, 256, 0, stream>>>(cb, cbn);
  k_prep_ab2<<<C1, 256, 0, stream>>>(db1, dw2, db2, ab1, ab2);
  k_prep_c<<<1, 256, 0, stream>>>(dw3, db3, ab2, cconst);
  k_enc12<<<SS, 256, 0, stream>>>(audio, ew1, eb1, ew2, eb2, h2c);
  k_h2x<<<384, 256, 0, stream>>>(h2c, h2xh, h2xl);
  gemm_h3<<<dim3(112, 4), 64, 0, stream>>>(ew3, h2xh, h2xl, eb3, h3h, h3l);
  gemm_scores<<<dim3(16, 4, 14), 64, 0, stream>>>(cb, h3h, h3l, cbn, scores);
  k_argmin<<<NCBK * NN, 64, 0, stream>>>(scores, codes);
  // dw1t overlaps h3h/h3l/scores memory: must launch AFTER k_argmin (stream-ordered)
  k_dw1t<<<dim3(112, 40), 256, 0, stream>>>(dw1, dw1t);
  k_gather_qbf<<<3584, 256, 0, stream>>>(cb, codes, qbf);
  gemm_a1_mfma<<<dim3(40, 4), 256, 0, stream>>>(dw1t, qbf, a1raw);
  k_dec2<<<NN, 256, 0, stream>>>(a1raw, ab1, db1, dw2, db2, a2act);
  k_fill<<<256, 256, 0, stream>>>(outp, cconst);
  k_dec3<<<NN, 256, 0, stream>>>(a2act, ab2, dw3, db3, outp);
}

// Round 5
// 616.457 us; speedup vs baseline: 1.4307x; 1.0284x over previous
//
#include <hip/hip_runtime.h>
#include <hip/hip_bf16.h>
#include <math.h>

#define T_IN 98304
#define SS 128
#define NBATCH 2
#define NN 256          // NBATCH*SS
#define C1 256
#define C2 512
#define C3 7168
#define NCBK 14
#define DIMV 512
#define VOC 1024
#define TOUT 97537
#define HOP 768

// ws layout (float offsets)
#define OFF_CBN    0L          // 14336
#define OFF_AB1    14336L      // 512
#define OFF_AB2    14848L      // 256
#define OFF_CCONST 15104L      // 16
#define OFF_H2C    15120L      // 131072   (n*512+ic), n=b*128+s
#define OFF_H2XH   146192L     // 196608 fl (ushort [256][1536] bf16-hi)
#define OFF_H2XL   342800L     // 196608 fl (bf16-lo)
#define OFF_H3H    539408L     // 917504 fl (ushort [256][7168] bf16-hi)
#define OFF_H3L    1456912L    // 917504 fl
#define OFF_SCORES 2374416L    // 3670016  ((k*256+n)*1024 + v)
// dw1t (bf16 [2560][7168] = 9175040 fl) OVERLAPS h3h/h3l/scores: all dead
// before k_dw1t runs (launched after k_argmin; same stream serializes).
#define OFF_DW1T   539408L     // ends 9714448
// Xh/Xl (bf16 [2304][2560] each = 2949120 fl each) OVERLAP dw1t: dw1t is dead
// after gemm_a1_mfma; k_x2 launches after it (same stream serializes).
#define OFF_XH     539408L     // ends 3488528
#define OFF_XL     3488528L    // ends 6437648
#define OFF_CODES  9714448L    // 3584 ints
#define OFF_QBF    9718032L    // 917504 fl (bf16 [256][7168])
#define OFF_A1RAW  10635536L   // 655360   ((n*5+j)*512 + c)  pre-bias/relu
#define OFF_A2ACT  11290896L   // 589824   ((n*9+u)*256 + o)  post-relu
// total 11880720 floats = 47.5 MB

typedef __attribute__((ext_vector_type(8))) short short8;
typedef __attribute__((ext_vector_type(4))) float f32x4;

static __device__ inline ushort f2bf(float x) {
  __hip_bfloat16 h = __float2bfloat16(x);
  return *reinterpret_cast<ushort*>(&h);
}

// exact 2-term split: x = hi + lo + O(2^-16 |x|); truncation split, residual exact
static __device__ inline void split8(const float4 x0, const float4 x1,
                                     short8& h, short8& l) {
  float xs[8] = {x0.x, x0.y, x0.z, x0.w, x1.x, x1.y, x1.z, x1.w};
  #pragma unroll
  for (int e = 0; e < 8; ++e) {
    uint b = __float_as_uint(xs[e]);
    h[e] = (short)(b >> 16);
    float r = xs[e] - __uint_as_float(b & 0xffff0000u);
    l[e] = (short)(__float_as_uint(r) >> 16);
  }
}

// ---------------- prep: codebook norms ----------------
__global__ void k_cbn(const float* __restrict__ cb, float* __restrict__ cbn) {
  int row = blockIdx.x * 4 + (threadIdx.x >> 6);
  int lane = threadIdx.x & 63;
  const float* p = cb + (long)row * DIMV;
  float s = 0.f;
  for (int d = lane; d < DIMV; d += 64) { float x = p[d]; s += x * x; }
  for (int off = 32; off; off >>= 1) s += __shfl_down(s, off);
  if (lane == 0) cbn[row] = s;
}

// ---------------- prep A: ab1 = relu(db1); ab2[o] = relu(db2[o]+sum_c W(o,c)*ab1[c])
__global__ __launch_bounds__(256) void k_prep_ab2(const float* __restrict__ db1,
    const float* __restrict__ dw2, const float* __restrict__ db2,
    float* __restrict__ ab1, float* __restrict__ ab2) {
  __shared__ float red[256];
  int o = blockIdx.x, t = threadIdx.x;
  if (o == 0) { ab1[t] = fmaxf(db1[t], 0.f); ab1[t + 256] = fmaxf(db1[t + 256], 0.f); }
  const float* wp = dw2 + (long)o * C2 * 5;
  float acc = 0.f;
  #pragma unroll
  for (int h = 0; h < 2; ++h) {
    int c = t + h * 256;
    const float* p = wp + c * 5;
    float wsum = p[0] + p[1] + p[2] + p[3] + p[4];
    acc = fmaf(wsum, fmaxf(db1[c], 0.f), acc);
  }
  red[t] = acc;
  __syncthreads();
  for (int off = 128; off; off >>= 1) {
    if (t < off) red[t] += red[t + off];
    __syncthreads();
  }
  if (t == 0) ab2[o] = fmaxf(red[0] + db2[o], 0.f);
}

// ---------------- prep B: cconst = tanh(db3 + sum_o (sum_j dw3[o][j]) * ab2[o]) ----
__global__ __launch_bounds__(256) void k_prep_c(const float* __restrict__ dw3,
    const float* __restrict__ db3, const float* __restrict__ ab2,
    float* __restrict__ cconst) {
  __shared__ float red[256];
  int t = threadIdx.x;
  float wsum3 = 0.f;
  #pragma unroll
  for (int j = 0; j < 7; ++j) wsum3 += dw3[t*7+j];
  red[t] = wsum3 * ab2[t];
  __syncthreads();
  for (int off = 128; off; off >>= 1) {
    if (t < off) red[t] += red[t + off];
    __syncthreads();
  }
  if (t == 0) cconst[0] = tanhf(red[0] + db3[0]);
}

// ---------------- fused encoder conv1 (k7,p3) + conv2 (k5,s768,p2) ----------------
__global__ __launch_bounds__(256) void k_enc12(const float* __restrict__ audio,
    const float* __restrict__ ew1, const float* __restrict__ eb1,
    const float* __restrict__ ew2, const float* __restrict__ eb2,
    float* __restrict__ h2c) {
  __shared__ float h1s[NBATCH][5][C1];
  int s = blockIdx.x;
  int ic = threadIdx.x;
  float w1[7];
  #pragma unroll
  for (int j = 0; j < 7; ++j) w1[j] = ew1[ic*7+j];
  float b1 = eb1[ic];
  for (int b = 0; b < NBATCH; ++b) {
    const float* ap = audio + (long)b * T_IN;
    #pragma unroll
    for (int jj = 0; jj < 5; ++jj) {
      int tcol = HOP * s + jj - 2;
      float v = 0.f;
      if (tcol >= 0) {
        float acc = b1;
        #pragma unroll
        for (int j = 0; j < 7; ++j) {
          int ai = tcol + j - 3;
          float a = (ai >= 0 && ai < T_IN) ? ap[ai] : 0.f;
          acc = fmaf(w1[j], a, acc);
        }
        v = fmaxf(acc, 0.f);
      }
      h1s[b][jj][ic] = v;
    }
  }
  __syncthreads();
  for (int oo = 0; oo < 2; ++oo) {
    int oc = threadIdx.x + oo * 256;
    float acc0 = eb2[oc], acc1 = acc0;
    const float* wp = ew2 + (long)oc * C1 * 5;
    for (int icc = 0; icc < C1; ++icc) {
      #pragma unroll
      for (int jj = 0; jj < 5; ++jj) {
        float w = wp[icc*5+jj];
        acc0 = fmaf(w, h1s[0][jj][icc], acc0);
        acc1 = fmaf(w, h1s[1][jj][icc], acc1);
      }
    }
    h2c[(long)(0*SS + s)*C2 + oc] = fmaxf(acc0, 0.f);
    h2c[(long)(1*SS + s)*C2 + oc] = fmaxf(acc1, 0.f);
  }
}

// ---------------- im2col for conv3 (k3,p1), written as bf16 hi/lo split ----------
__global__ void k_h2x(const float* __restrict__ h2c, ushort* __restrict__ h2xh,
                      ushort* __restrict__ h2xl) {
  int idx = blockIdx.x * 256 + threadIdx.x;
  const int total = NN * 1536;
  for (; idx < total; idx += gridDim.x * 256) {
    int n = idx / 1536, r = idx - n * 1536;
    int ic = r / 3, j = r - ic * 3;
    int s2 = (n & 127) + j - 1;
    int b = n >> 7;
    float v = (s2 >= 0 && s2 < SS) ? h2c[(long)(b*SS + s2)*C2 + ic] : 0.f;
    uint bi = __float_as_uint(v);
    h2xh[idx] = (ushort)(bi >> 16);
    float rr = v - __uint_as_float(bi & 0xffff0000u);
    h2xl[idx] = (ushort)(__float_as_uint(rr) >> 16);
  }
}

// ---------------- S1: h3 = ew3 . h2x^T + eb3, 3xBF16 MFMA, no-LDS 1-wave blocks ----
__global__ __launch_bounds__(64) void gemm_h3(const float* __restrict__ A,
    const ushort* __restrict__ Bh, const ushort* __restrict__ Bl,
    const float* __restrict__ eb3, ushort* __restrict__ h3h, ushort* __restrict__ h3l) {
  const int t = threadIdx.x;
  const int l15 = t & 15, quad = t >> 4;
  const int m0 = blockIdx.x * 64, n0 = blockIdx.y * 64;
  f32x4 acc[4][4] = {};
  const float*  aB = A  + (long)(m0 + l15) * 1536 + quad * 8;
  const ushort* bhB = Bh + (long)(n0 + l15) * 1536 + quad * 8;
  const ushort* blB = Bl + (long)(n0 + l15) * 1536 + quad * 8;
  for (int k0 = 0; k0 < 1536; k0 += 32) {
    short8 ah[4], al[4], bh[4], bl[4];
    #pragma unroll
    for (int f = 0; f < 4; ++f) {
      const float* ap = aB + (long)f * 16 * 1536 + k0;
      float4 x0 = *(const float4*)ap;
      float4 x1 = *(const float4*)(ap + 4);
      split8(x0, x1, ah[f], al[f]);
      bh[f] = *(const short8*)(bhB + (long)f * 16 * 1536 + k0);
      bl[f] = *(const short8*)(blB + (long)f * 16 * 1536 + k0);
    }
    #pragma unroll
    for (int i = 0; i < 4; ++i)
      #pragma unroll
      for (int j = 0; j < 4; ++j) {
        acc[i][j] = __builtin_amdgcn_mfma_f32_16x16x32_bf16(ah[i], bh[j], acc[i][j], 0, 0, 0);
        acc[i][j] = __builtin_amdgcn_mfma_f32_16x16x32_bf16(ah[i], bl[j], acc[i][j], 0, 0, 0);
        acc[i][j] = __builtin_amdgcn_mfma_f32_16x16x32_bf16(al[i], bh[j], acc[i][j], 0, 0, 0);
      }
  }
  #pragma unroll
  for (int i = 0; i < 4; ++i) {
    const int mbase = m0 + i * 16 + quad * 4;
    float4 bias = *(const float4*)(eb3 + mbase);
    #pragma unroll
    for (int j = 0; j < 4; ++j) {
      const int n = n0 + j * 16 + l15;
      float v0 = acc[i][j][0] + bias.x;
      float v1 = acc[i][j][1] + bias.y;
      float v2 = acc[i][j][2] + bias.z;
      float v3 = acc[i][j][3] + bias.w;
      uint b0 = __float_as_uint(v0), b1 = __float_as_uint(v1);
      uint b2 = __float_as_uint(v2), b3 = __float_as_uint(v3);
      uint2 hp;
      hp.x = (b0 >> 16) | (b1 & 0xffff0000u);
      hp.y = (b2 >> 16) | (b3 & 0xffff0000u);
      float r0 = v0 - __uint_as_float(b0 & 0xffff0000u);
      float r1 = v1 - __uint_as_float(b1 & 0xffff0000u);
      float r2 = v2 - __uint_as_float(b2 & 0xffff0000u);
      float r3 = v3 - __uint_as_float(b3 & 0xffff0000u);
      uint2 lp;
      lp.x = (__float_as_uint(r0) >> 16) | (__float_as_uint(r1) & 0xffff0000u);
      lp.y = (__float_as_uint(r2) >> 16) | (__float_as_uint(r3) & 0xffff0000u);
      long off = (long)n * C3 + mbase;
      *(uint2*)(h3h + off) = hp;
      *(uint2*)(h3l + off) = lp;
    }
  }
}

// ---------------- S2: scores = cbn - 2*cb.h3^T, 3xBF16 MFMA, no-LDS 1-wave blocks --
__global__ __launch_bounds__(64) void gemm_scores(const float* __restrict__ cb,
    const ushort* __restrict__ h3h, const ushort* __restrict__ h3l,
    const float* __restrict__ cbn, float* __restrict__ scores) {
  const int t = threadIdx.x;
  const int l15 = t & 15, quad = t >> 4;
  const int m0 = blockIdx.x * 64, n0 = blockIdx.y * 64, z = blockIdx.z;
  f32x4 acc[4][4] = {};
  const float*  aB = cb + (long)z * VOC * DIMV + (long)(m0 + l15) * 512 + quad * 8;
  const ushort* bhB = h3h + (long)(n0 + l15) * C3 + z * 512 + quad * 8;
  const ushort* blB = h3l + (long)(n0 + l15) * C3 + z * 512 + quad * 8;
  for (int k0 = 0; k0 < 512; k0 += 32) {
    short8 ah[4], al[4], bh[4], bl[4];
    #pragma unroll
    for (int f = 0; f < 4; ++f) {
      const float* ap = aB + (long)f * 16 * 512 + k0;
      float4 x0 = *(const float4*)ap;
      float4 x1 = *(const float4*)(ap + 4);
      split8(x0, x1, ah[f], al[f]);
      bh[f] = *(const short8*)(bhB + (long)f * 16 * C3 + k0);
      bl[f] = *(const short8*)(blB + (long)f * 16 * C3 + k0);
    }
    #pragma unroll
    for (int i = 0; i < 4; ++i)
      #pragma unroll
      for (int j = 0; j < 4; ++j) {
        acc[i][j] = __builtin_amdgcn_mfma_f32_16x16x32_bf16(ah[i], bh[j], acc[i][j], 0, 0, 0);
        acc[i][j] = __builtin_amdgcn_mfma_f32_16x16x32_bf16(ah[i], bl[j], acc[i][j], 0, 0, 0);
        acc[i][j] = __builtin_amdgcn_mfma_f32_16x16x32_bf16(al[i], bh[j], acc[i][j], 0, 0, 0);
      }
  }
  #pragma unroll
  for (int i = 0; i < 4; ++i) {
    const int vbase = m0 + i * 16 + quad * 4;
    float4 cn = *(const float4*)(cbn + z * VOC + vbase);
    #pragma unroll
    for (int j = 0; j < 4; ++j) {
      const int n = n0 + j * 16 + l15;
      float4 out;
      out.x = cn.x - 2.f * acc[i][j][0];
      out.y = cn.y - 2.f * acc[i][j][1];
      out.z = cn.z - 2.f * acc[i][j][2];
      out.w = cn.w - 2.f * acc[i][j][3];
      *(float4*)(scores + ((long)z * NN + n) * VOC + vbase) = out;
    }
  }
}

// ---------------- argmin over 1024 codes, numpy tie-break (lowest v) ----------------
__global__ void k_argmin(const float* __restrict__ scores, int* __restrict__ codes) {
  int row = blockIdx.x;          // k*256+n
  int lane = threadIdx.x;        // 64
  const float* p = scores + (long)row * VOC;
  float best = 3.4e38f; int bi = 0;
  for (int i = 0; i < 16; ++i) {
    int v = i * 64 + lane;
    float x = p[v];
    if (x < best) { best = x; bi = v; }
  }
  for (int off = 32; off; off >>= 1) {
    float ob = __shfl_down(best, off);
    int oi = __shfl_down(bi, off);
    if (ob < best || (ob == best && oi < bi)) { best = ob; bi = oi; }
  }
  if (lane == 0) codes[row] = bi;
}

// ---------------- transpose+convert dw1 [7168][2560] fp32 -> dw1t [2560][7168] bf16 ----
__global__ __launch_bounds__(256) void k_dw1t(const float* __restrict__ dw1,
                                              ushort* __restrict__ dw1t) {
  __shared__ __align__(16) ushort T[64 * 72];   // [m][k] tile, pitch 72
  int t = threadIdx.x;
  int k0 = blockIdx.x * 64, m0 = blockIdx.y * 64;
  int kk = t >> 2, mj = (t & 3) * 16;
  const float* src = dw1 + (long)(k0 + kk) * 2560 + m0 + mj;
  float x[16];
  *(float4*)&x[0]  = *(const float4*)(src);
  *(float4*)&x[4]  = *(const float4*)(src + 4);
  *(float4*)&x[8]  = *(const float4*)(src + 8);
  *(float4*)&x[12] = *(const float4*)(src + 12);
  #pragma unroll
  for (int l = 0; l < 16; ++l)
    T[(mj + l) * 72 + kk] = f2bf(x[l]);
  __syncthreads();
  int mo = t >> 2, kc = (t & 3) * 16;
  uint4 u0 = *(const uint4*)&T[mo * 72 + kc];
  uint4 u1 = *(const uint4*)&T[mo * 72 + kc + 8];
  ushort* dst = dw1t + (long)(m0 + mo) * C3 + k0 + kc;
  *(uint4*)dst = u0;
  *(uint4*)(dst + 8) = u1;
}

// ---------------- gather q as bf16: qbf[n][k*512+d] = bf16(cb[k, code, d]) ----------
__global__ void k_gather_qbf(const float* __restrict__ cb, const int* __restrict__ codes,
                             ushort* __restrict__ qbf) {
  int idx = blockIdx.x * 256 + threadIdx.x;      // pair index
  const int total = NN * C3 / 2;                 // 917504
  if (idx >= total) return;
  int n = idx / 3584, rr = idx - n * 3584;       // rr = k*256 + dp
  int k = rr >> 8, dp = rr & 255;
  int code = codes[k * NN + n];
  const float* s = cb + ((long)(k * VOC + code)) * DIMV + dp * 2;
  uint lo = f2bf(s[0]), hi = f2bf(s[1]);
  ((uint*)qbf)[idx] = lo | (hi << 16);
}

// ---------------- decoder convT GEMM via MFMA bf16 ----------------
__global__ __launch_bounds__(256) void gemm_a1_mfma(const ushort* __restrict__ dw1t,
    const ushort* __restrict__ qbf, float* __restrict__ a1raw) {
  __shared__ __align__(16) ushort As[64 * 40];
  __shared__ __align__(16) ushort Bs[64 * 40];
  const int tid = threadIdx.x;
  const int w = tid >> 6, lane = tid & 63;
  const int wm = w & 1, wn = w >> 1;
  const int m0 = blockIdx.x * 64, n0 = blockIdx.y * 64;
  const int l15 = lane & 15, quad = lane >> 4;
  const int r = tid >> 2, koff = (tid & 3) * 8;
  const ushort* aP = dw1t + (long)(m0 + r) * C3 + koff;
  const ushort* bP = qbf + (long)(n0 + r) * C3 + koff;
  f32x4 acc[2][2] = {};
  const int aoff0 = (wm * 32 + l15) * 40 + quad * 8;
  const int aoff1 = (wm * 32 + 16 + l15) * 40 + quad * 8;
  const int boff0 = (wn * 32 + l15) * 40 + quad * 8;
  const int boff1 = (wn * 32 + 16 + l15) * 40 + quad * 8;
  const int soff = r * 40 + koff;
  for (int k0 = 0; k0 < C3; k0 += 32) {
    uint4 av = *(const uint4*)(aP + k0);
    uint4 bv = *(const uint4*)(bP + k0);
    *(uint4*)&As[soff] = av;
    *(uint4*)&Bs[soff] = bv;
    __syncthreads();
    short8 a0 = *(const short8*)&As[aoff0];
    short8 a1 = *(const short8*)&As[aoff1];
    short8 b0 = *(const short8*)&Bs[boff0];
    short8 b1 = *(const short8*)&Bs[boff1];
    acc[0][0] = __builtin_amdgcn_mfma_f32_16x16x32_bf16(a0, b0, acc[0][0], 0, 0, 0);
    acc[0][1] = __builtin_amdgcn_mfma_f32_16x16x32_bf16(a0, b1, acc[0][1], 0, 0, 0);
    acc[1][0] = __builtin_amdgcn_mfma_f32_16x16x32_bf16(a1, b0, acc[1][0], 0, 0, 0);
    acc[1][1] = __builtin_amdgcn_mfma_f32_16x16x32_bf16(a1, b1, acc[1][1], 0, 0, 0);
    __syncthreads();
  }
  #pragma unroll
  for (int i = 0; i < 2; ++i)
    #pragma unroll
    for (int j = 0; j < 2; ++j)
      #pragma unroll
      for (int reg = 0; reg < 4; ++reg) {
        int m = m0 + wm * 32 + i * 16 + quad * 4 + reg;
        int n = n0 + wn * 32 + j * 16 + l15;
        int c = m / 5, jj = m - c * 5;
        a1raw[((long)(n * 5 + jj)) * C2 + c] = acc[i][j][reg];
      }
}

// ---------------- k_x2: build conv2 im2col X (bf16 hi/lo) from a1raw/ab1 ----------
// X[nu=n*9+u][ck=c*5+jj] = P[n][c][w=u+jj] where
//   tc = 768*(n&127) - 6 + w;  tc out of [0,TOUT) -> 0
//   w in [4,8] -> relu(db1[c] + a1raw[(n*5+(w-4))*512+c]); else -> ab1[c]
__global__ void k_x2(const float* __restrict__ a1raw, const float* __restrict__ ab1g,
                     const float* __restrict__ db1, ushort* __restrict__ Xh,
                     ushort* __restrict__ Xl) {
  int idx = blockIdx.x * 256 + threadIdx.x;
  const int total = 2304 * 2560;
  for (; idx < total; idx += gridDim.x * 256) {
    int nu = idx / 2560, ck = idx - nu * 2560;
    int n = nu / 9, u = nu - n * 9;
    int c = ck / 5, jj = ck - c * 5;
    int w = u + jj;
    int s = n & 127;
    int tc = HOP * s - 6 + w;
    float v;
    if (tc < 0 || tc > TOUT - 1) v = 0.f;
    else if (w >= 4 && w <= 8)
      v = fmaxf(db1[c] + a1raw[((long)(n * 5 + (w - 4))) * C2 + c], 0.f);
    else v = ab1g[c];
    uint bi = __float_as_uint(v);
    Xh[idx] = (ushort)(bi >> 16);
    float rr = v - __uint_as_float(bi & 0xffff0000u);
    Xl[idx] = (ushort)(__float_as_uint(rr) >> 16);
  }
}

// ---------------- decoder conv2 as GEMM: a2act = relu(db2 + dw2 . X^T) ----------
// A = dw2 fp32 [256][2560] (OTF split), B = X splits [2304][2560]
// out a2act[nu][o];  3xBF16 MFMA, no-LDS 1-wave blocks, grid (4, 36)
__global__ __launch_bounds__(64) void gemm_dec2(const float* __restrict__ dw2,
    const ushort* __restrict__ Xh, const ushort* __restrict__ Xl,
    const float* __restrict__ db2, float* __restrict__ a2act) {
  const int t = threadIdx.x;
  const int l15 = t & 15, quad = t >> 4;
  const int m0 = blockIdx.x * 64, n0 = blockIdx.y * 64;
  f32x4 acc[4][4] = {};
  const float*  aB = dw2 + (long)(m0 + l15) * 2560 + quad * 8;
  const ushort* bhB = Xh + (long)(n0 + l15) * 2560 + quad * 8;
  const ushort* blB = Xl + (long)(n0 + l15) * 2560 + quad * 8;
  for (int k0 = 0; k0 < 2560; k0 += 32) {
    short8 ah[4], al[4], bh[4], bl[4];
    #pragma unroll
    for (int f = 0; f < 4; ++f) {
      const float* ap = aB + (long)f * 16 * 2560 + k0;
      float4 x0 = *(const float4*)ap;
      float4 x1 = *(const float4*)(ap + 4);
      split8(x0, x1, ah[f], al[f]);
      bh[f] = *(const short8*)(bhB + (long)f * 16 * 2560 + k0);
      bl[f] = *(const short8*)(blB + (long)f * 16 * 2560 + k0);
    }
    #pragma unroll
    for (int i = 0; i < 4; ++i)
      #pragma unroll
      for (int j = 0; j < 4; ++j) {
        acc[i][j] = __builtin_amdgcn_mfma_f32_16x16x32_bf16(ah[i], bh[j], acc[i][j], 0, 0, 0);
        acc[i][j] = __builtin_amdgcn_mfma_f32_16x16x32_bf16(ah[i], bl[j], acc[i][j], 0, 0, 0);
        acc[i][j] = __builtin_amdgcn_mfma_f32_16x16x32_bf16(al[i], bh[j], acc[i][j], 0, 0, 0);
      }
  }
  #pragma unroll
  for (int i = 0; i < 4; ++i) {
    const int obase = m0 + i * 16 + quad * 4;
    float4 bias = *(const float4*)(db2 + obase);
    #pragma unroll
    for (int j = 0; j < 4; ++j) {
      const int nu = n0 + j * 16 + l15;
      float4 out;
      out.x = fmaxf(acc[i][j][0] + bias.x, 0.f);
      out.y = fmaxf(acc[i][j][1] + bias.y, 0.f);
      out.z = fmaxf(acc[i][j][2] + bias.z, 0.f);
      out.w = fmaxf(acc[i][j][3] + bias.w, 0.f);
      *(float4*)(a2act + (long)nu * C1 + obase) = out;
    }
  }
}

// ---------------- fill output with the constant tanh value ----------------
__global__ void k_fill(float* __restrict__ outp, const float* __restrict__ cconst) {
  float v = cconst[0];
  int idx = blockIdx.x * 256 + threadIdx.x;
  const int total = NBATCH * TOUT;
  for (; idx < total; idx += gridDim.x * 256) outp[idx] = v;
}

// ---------------- decoder conv3+tanh on 15 active cols per (b,s) ----------------
__global__ __launch_bounds__(256) void k_dec3(const float* __restrict__ a2act,
    const float* __restrict__ ab2g, const float* __restrict__ dw3,
    const float* __restrict__ db3, float* __restrict__ outp) {
  __shared__ float sa2[9 * C1];
  __shared__ float sb[C1];
  int n = blockIdx.x;
  int s = n & 127, b = n >> 7;
  int t = threadIdx.x;
  for (int i = t; i < 9 * C1; i += 256) sa2[i] = a2act[(long)n * 9 * C1 + i];
  sb[t] = ab2g[t];
  __syncthreads();
  int wv = t >> 6, lane = t & 63;
  float b3 = db3[0];
  for (int w15 = wv; w15 < 15; w15 += 4) {
    int tc = HOP * s - 7 + w15;
    if (tc < 0 || tc > TOUT - 1) continue;
    float part = 0.f;
    for (int cc = lane; cc < C1; cc += 64) {
      #pragma unroll
      for (int j = 0; j < 7; ++j) {
        int wcol = tc + j - 3;
        float x;
        if (wcol < 0 || wcol > TOUT - 1) x = 0.f;
        else {
          int du = wcol - (HOP * s - 4);
          x = (du >= 0 && du <= 8) ? sa2[du * C1 + cc] : sb[cc];
        }
        part = fmaf(dw3[cc*7+j], x, part);
      }
    }
    for (int off = 32; off; off >>= 1) part += __shfl_down(part, off);
    if (lane == 0) outp[(long)b * TOUT + tc] = tanhf(part + b3);
  }
}

extern "C" void kernel_launch(void* const* d_in, const int* in_sizes, int n_in,
                              void* d_out, int out_size, void* d_ws, size_t ws_size,
                              hipStream_t stream) {
  const float* audio = (const float*)d_in[0];
  const float* cb    = (const float*)d_in[1];
  const float* ew1   = (const float*)d_in[2];
  const float* eb1   = (const float*)d_in[3];
  const float* ew2   = (const float*)d_in[4];
  const float* eb2   = (const float*)d_in[5];
  const float* ew3   = (const float*)d_in[6];
  const float* eb3   = (const float*)d_in[7];
  const float* dw1   = (const float*)d_in[8];
  const float* db1   = (const float*)d_in[9];
  const float* dw2   = (const float*)d_in[10];
  const float* db2   = (const float*)d_in[11];
  const float* dw3   = (const float*)d_in[12];
  const float* db3   = (const float*)d_in[13];
  float* outp = (float*)d_out;
  float* ws = (float*)d_ws;

  float*  cbn    = ws + OFF_CBN;
  float*  ab1    = ws + OFF_AB1;
  float*  ab2    = ws + OFF_AB2;
  float*  cconst = ws + OFF_CCONST;
  float*  h2c    = ws + OFF_H2C;
  ushort* h2xh   = (ushort*)(ws + OFF_H2XH);
  ushort* h2xl   = (ushort*)(ws + OFF_H2XL);
  ushort* h3h    = (ushort*)(ws + OFF_H3H);
  ushort* h3l    = (ushort*)(ws + OFF_H3L);
  float*  scores = ws + OFF_SCORES;
  ushort* dw1t   = (ushort*)(ws + OFF_DW1T);
  ushort* Xh     = (ushort*)(ws + OFF_XH);
  ushort* Xl     = (ushort*)(ws + OFF_XL);
  int*    codes  = (int*)(ws + OFF_CODES);
  ushort* qbf    = (ushort*)(ws + OFF_QBF);
  float*  a1raw  = ws + OFF_A1RAW;
  float*  a2act  = ws + OFF_A2ACT;

  k_cbn<<<3584, 256, 0, stream>>>(cb, cbn);
  k_prep_ab2<<<C1, 256, 0, stream>>>(db1, dw2, db2, ab1, ab2);
  k_prep_c<<<1, 256, 0, stream>>>(dw3, db3, ab2, cconst);
  k_enc12<<<SS, 256, 0, stream>>>(audio, ew1, eb1, ew2, eb2, h2c);
  k_h2x<<<384, 256, 0, stream>>>(h2c, h2xh, h2xl);
  gemm_h3<<<dim3(112, 4), 64, 0, stream>>>(ew3, h2xh, h2xl, eb3, h3h, h3l);
  gemm_scores<<<dim3(16, 4, 14), 64, 0, stream>>>(cb, h3h, h3l, cbn, scores);
  k_argmin<<<NCBK * NN, 64, 0, stream>>>(scores, codes);
  // dw1t overlaps h3h/h3l/scores memory: must launch AFTER k_argmin (stream-ordered)
  k_dw1t<<<dim3(112, 40), 256, 0, stream>>>(dw1, dw1t);
  k_gather_qbf<<<3584, 256, 0, stream>>>(cb, codes, qbf);
  gemm_a1_mfma<<<dim3(40, 4), 256, 0, stream>>>(dw1t, qbf, a1raw);
  // Xh/Xl overlap dw1t memory: must launch AFTER gemm_a1_mfma (stream-ordered)
  k_x2<<<4096, 256, 0, stream>>>(a1raw, ab1, db1, Xh, Xl);
  gemm_dec2<<<dim3(4, 36), 64, 0, stream>>>(dw2, Xh, Xl, db2, a2act);
  k_fill<<<256, 256, 0, stream>>>(outp, cconst);
  k_dec3<<<NN, 256, 0, stream>>>(a2act, ab2, dw3, db3, outp);
}

// Round 6
// 555.249 us; speedup vs baseline: 1.5884x; 1.1102x over previous
//
#include <hip/hip_runtime.h>
#include <hip/hip_bf16.h>
#include <math.h>

#define T_IN 98304
#define SS 128
#define NBATCH 2
#define NN 256          // NBATCH*SS
#define C1 256
#define C2 512
#define C3 7168
#define NCBK 14
#define DIMV 512
#define VOC 1024
#define TOUT 97537
#define HOP 768

// ws layout (float offsets)
#define OFF_CBN    0L          // 14336
#define OFF_AB1    14336L      // 512
#define OFF_AB2    14848L      // 256
#define OFF_CCONST 15104L      // 16
#define OFF_H2C    15120L      // 131072   (n*512+ic), n=b*128+s
#define OFF_H2XH   146192L     // 196608 fl (ushort [256][1536] bf16-hi)
#define OFF_H2XL   342800L     // 196608 fl (bf16-lo)
#define OFF_H3H    539408L     // 917504 fl (ushort [256][7168] bf16-hi)
#define OFF_H3L    1456912L    // 917504 fl
#define OFF_SCORES 2374416L    // 3670016  ((k*256+n)*1024 + v)
// X1h/X1l (bf16 [256][1280] = 163840 fl each) OVERLAP scores region: X1 is dead
// before gemm_scores writes scores (same stream serializes).
#define OFF_X1H    2374416L    // ends 2538256
#define OFF_X1L    2538256L    // ends 2702096
// dw1t (bf16 [2560][7168] = 9175040 fl) OVERLAPS h3h/h3l/scores: all dead
// before k_dw1t runs (launched after k_argmin; same stream serializes).
#define OFF_DW1T   539408L     // ends 9714448
// Xh/Xl (bf16 [2304][2560] each = 2949120 fl each) OVERLAP dw1t: dw1t is dead
// after gemm_a1_mfma; k_x2 launches after it (same stream serializes).
#define OFF_XH     539408L     // ends 3488528
#define OFF_XL     3488528L    // ends 6437648
#define OFF_CODES  9714448L    // 3584 ints
#define OFF_QBF    9718032L    // 917504 fl (bf16 [256][7168])
#define OFF_A1RAW  10635536L   // 655360   ((n*5+j)*512 + c)  pre-bias/relu
#define OFF_A2ACT  11290896L   // 589824   ((n*9+u)*256 + o)  post-relu
// total 11880720 floats = 47.5 MB

typedef __attribute__((ext_vector_type(8))) short short8;
typedef __attribute__((ext_vector_type(4))) float f32x4;

static __device__ inline ushort f2bf(float x) {
  __hip_bfloat16 h = __float2bfloat16(x);
  return *reinterpret_cast<ushort*>(&h);
}

// exact 2-term split: x = hi + lo + O(2^-16 |x|); truncation split, residual exact
static __device__ inline void split8(const float4 x0, const float4 x1,
                                     short8& h, short8& l) {
  float xs[8] = {x0.x, x0.y, x0.z, x0.w, x1.x, x1.y, x1.z, x1.w};
  #pragma unroll
  for (int e = 0; e < 8; ++e) {
    uint b = __float_as_uint(xs[e]);
    h[e] = (short)(b >> 16);
    float r = xs[e] - __uint_as_float(b & 0xffff0000u);
    l[e] = (short)(__float_as_uint(r) >> 16);
  }
}

// ---------------- prep: codebook norms ----------------
__global__ void k_cbn(const float* __restrict__ cb, float* __restrict__ cbn) {
  int row = blockIdx.x * 4 + (threadIdx.x >> 6);
  int lane = threadIdx.x & 63;
  const float* p = cb + (long)row * DIMV;
  float s = 0.f;
  for (int d = lane; d < DIMV; d += 64) { float x = p[d]; s += x * x; }
  for (int off = 32; off; off >>= 1) s += __shfl_down(s, off);
  if (lane == 0) cbn[row] = s;
}

// ---------------- prep A: ab1 = relu(db1); ab2[o] = relu(db2[o]+sum_c W(o,c)*ab1[c])
__global__ __launch_bounds__(256) void k_prep_ab2(const float* __restrict__ db1,
    const float* __restrict__ dw2, const float* __restrict__ db2,
    float* __restrict__ ab1, float* __restrict__ ab2) {
  __shared__ float red[256];
  int o = blockIdx.x, t = threadIdx.x;
  if (o == 0) { ab1[t] = fmaxf(db1[t], 0.f); ab1[t + 256] = fmaxf(db1[t + 256], 0.f); }
  const float* wp = dw2 + (long)o * C2 * 5;
  float acc = 0.f;
  #pragma unroll
  for (int h = 0; h < 2; ++h) {
    int c = t + h * 256;
    const float* p = wp + c * 5;
    float wsum = p[0] + p[1] + p[2] + p[3] + p[4];
    acc = fmaf(wsum, fmaxf(db1[c], 0.f), acc);
  }
  red[t] = acc;
  __syncthreads();
  for (int off = 128; off; off >>= 1) {
    if (t < off) red[t] += red[t + off];
    __syncthreads();
  }
  if (t == 0) ab2[o] = fmaxf(red[0] + db2[o], 0.f);
}

// ---------------- prep B: cconst = tanh(db3 + sum_o (sum_j dw3[o][j]) * ab2[o]) ----
__global__ __launch_bounds__(256) void k_prep_c(const float* __restrict__ dw3,
    const float* __restrict__ db3, const float* __restrict__ ab2,
    float* __restrict__ cconst) {
  __shared__ float red[256];
  int t = threadIdx.x;
  float wsum3 = 0.f;
  #pragma unroll
  for (int j = 0; j < 7; ++j) wsum3 += dw3[t*7+j];
  red[t] = wsum3 * ab2[t];
  __syncthreads();
  for (int off = 128; off; off >>= 1) {
    if (t < off) red[t] += red[t + off];
    __syncthreads();
  }
  if (t == 0) cconst[0] = tanhf(red[0] + db3[0]);
}

// ---------------- encoder conv1 (k7,p3) at the 5 cols conv2 needs, as im2col ------
// X1[n][ic*5+jj] = h1[b][ic][768s+jj-2]  (0 if tcol<0: conv2 zero pad)
__global__ __launch_bounds__(256) void k_enc1(const float* __restrict__ audio,
    const float* __restrict__ ew1, const float* __restrict__ eb1,
    ushort* __restrict__ X1h, ushort* __restrict__ X1l) {
  int n = blockIdx.x, ic = threadIdx.x;
  int b = n >> 7, s = n & 127;
  const float* ap = audio + (long)b * T_IN;
  int base = HOP * s - 5;           // audio idx for window pos 0
  float a[11];
  #pragma unroll
  for (int w = 0; w < 11; ++w) {
    int ai = base + w;
    a[w] = (ai >= 0 && ai < T_IN) ? ap[ai] : 0.f;
  }
  float w1[7];
  #pragma unroll
  for (int j = 0; j < 7; ++j) w1[j] = ew1[ic*7+j];
  float b1 = eb1[ic];
  long off = (long)n * 1280 + ic * 5;
  #pragma unroll
  for (int jj = 0; jj < 5; ++jj) {
    int tcol = HOP * s + jj - 2;
    float v = 0.f;
    if (tcol >= 0) {
      float acc = b1;
      #pragma unroll
      for (int j = 0; j < 7; ++j) acc = fmaf(w1[j], a[jj + j], acc);
      v = fmaxf(acc, 0.f);
    }
    uint bi = __float_as_uint(v);
    X1h[off + jj] = (ushort)(bi >> 16);
    float r = v - __uint_as_float(bi & 0xffff0000u);
    X1l[off + jj] = (ushort)(__float_as_uint(r) >> 16);
  }
}

// ---------------- encoder conv2 as GEMM: h2c[n][oc] = relu(eb2 + ew2 . X1^T) ------
// A = ew2 fp32 [512][1280] (OTF split; layout [oc][ic*5+jj] matches X1's k),
// B = X1 splits [256][1280]; 3xBF16 MFMA, no-LDS 1-wave blocks, grid (16, 4)
__global__ __launch_bounds__(64) void gemm_enc2(const float* __restrict__ ew2,
    const ushort* __restrict__ X1h, const ushort* __restrict__ X1l,
    const float* __restrict__ eb2, float* __restrict__ h2c) {
  const int t = threadIdx.x;
  const int l15 = t & 15, quad = t >> 4;
  const int m0 = blockIdx.x * 32, n0 = blockIdx.y * 64;
  f32x4 acc[2][4] = {};
  const float*  aB = ew2 + (long)(m0 + l15) * 1280 + quad * 8;
  const ushort* bhB = X1h + (long)(n0 + l15) * 1280 + quad * 8;
  const ushort* blB = X1l + (long)(n0 + l15) * 1280 + quad * 8;
  for (int k0 = 0; k0 < 1280; k0 += 32) {
    short8 ah[2], al[2], bh[4], bl[4];
    #pragma unroll
    for (int f = 0; f < 2; ++f) {
      const float* ap = aB + (long)f * 16 * 1280 + k0;
      float4 x0 = *(const float4*)ap;
      float4 x1 = *(const float4*)(ap + 4);
      split8(x0, x1, ah[f], al[f]);
    }
    #pragma unroll
    for (int f = 0; f < 4; ++f) {
      bh[f] = *(const short8*)(bhB + (long)f * 16 * 1280 + k0);
      bl[f] = *(const short8*)(blB + (long)f * 16 * 1280 + k0);
    }
    #pragma unroll
    for (int i = 0; i < 2; ++i)
      #pragma unroll
      for (int j = 0; j < 4; ++j) {
        acc[i][j] = __builtin_amdgcn_mfma_f32_16x16x32_bf16(ah[i], bh[j], acc[i][j], 0, 0, 0);
        acc[i][j] = __builtin_amdgcn_mfma_f32_16x16x32_bf16(ah[i], bl[j], acc[i][j], 0, 0, 0);
        acc[i][j] = __builtin_amdgcn_mfma_f32_16x16x32_bf16(al[i], bh[j], acc[i][j], 0, 0, 0);
      }
  }
  #pragma unroll
  for (int i = 0; i < 2; ++i) {
    const int obase = m0 + i * 16 + quad * 4;
    float4 bias = *(const float4*)(eb2 + obase);
    #pragma unroll
    for (int j = 0; j < 4; ++j) {
      const int n = n0 + j * 16 + l15;
      float4 out;
      out.x = fmaxf(acc[i][j][0] + bias.x, 0.f);
      out.y = fmaxf(acc[i][j][1] + bias.y, 0.f);
      out.z = fmaxf(acc[i][j][2] + bias.z, 0.f);
      out.w = fmaxf(acc[i][j][3] + bias.w, 0.f);
      *(float4*)(h2c + (long)n * C2 + obase) = out;
    }
  }
}

// ---------------- im2col for conv3 (k3,p1), written as bf16 hi/lo split ----------
__global__ void k_h2x(const float* __restrict__ h2c, ushort* __restrict__ h2xh,
                      ushort* __restrict__ h2xl) {
  int idx = blockIdx.x * 256 + threadIdx.x;
  const int total = NN * 1536;
  for (; idx < total; idx += gridDim.x * 256) {
    int n = idx / 1536, r = idx - n * 1536;
    int ic = r / 3, j = r - ic * 3;
    int s2 = (n & 127) + j - 1;
    int b = n >> 7;
    float v = (s2 >= 0 && s2 < SS) ? h2c[(long)(b*SS + s2)*C2 + ic] : 0.f;
    uint bi = __float_as_uint(v);
    h2xh[idx] = (ushort)(bi >> 16);
    float rr = v - __uint_as_float(bi & 0xffff0000u);
    h2xl[idx] = (ushort)(__float_as_uint(rr) >> 16);
  }
}

// ---------------- S1: h3 = ew3 . h2x^T + eb3, 3xBF16 MFMA, no-LDS 1-wave blocks ----
__global__ __launch_bounds__(64) void gemm_h3(const float* __restrict__ A,
    const ushort* __restrict__ Bh, const ushort* __restrict__ Bl,
    const float* __restrict__ eb3, ushort* __restrict__ h3h, ushort* __restrict__ h3l) {
  const int t = threadIdx.x;
  const int l15 = t & 15, quad = t >> 4;
  const int m0 = blockIdx.x * 64, n0 = blockIdx.y * 64;
  f32x4 acc[4][4] = {};
  const float*  aB = A  + (long)(m0 + l15) * 1536 + quad * 8;
  const ushort* bhB = Bh + (long)(n0 + l15) * 1536 + quad * 8;
  const ushort* blB = Bl + (long)(n0 + l15) * 1536 + quad * 8;
  for (int k0 = 0; k0 < 1536; k0 += 32) {
    short8 ah[4], al[4], bh[4], bl[4];
    #pragma unroll
    for (int f = 0; f < 4; ++f) {
      const float* ap = aB + (long)f * 16 * 1536 + k0;
      float4 x0 = *(const float4*)ap;
      float4 x1 = *(const float4*)(ap + 4);
      split8(x0, x1, ah[f], al[f]);
      bh[f] = *(const short8*)(bhB + (long)f * 16 * 1536 + k0);
      bl[f] = *(const short8*)(blB + (long)f * 16 * 1536 + k0);
    }
    #pragma unroll
    for (int i = 0; i < 4; ++i)
      #pragma unroll
      for (int j = 0; j < 4; ++j) {
        acc[i][j] = __builtin_amdgcn_mfma_f32_16x16x32_bf16(ah[i], bh[j], acc[i][j], 0, 0, 0);
        acc[i][j] = __builtin_amdgcn_mfma_f32_16x16x32_bf16(ah[i], bl[j], acc[i][j], 0, 0, 0);
        acc[i][j] = __builtin_amdgcn_mfma_f32_16x16x32_bf16(al[i], bh[j], acc[i][j], 0, 0, 0);
      }
  }
  #pragma unroll
  for (int i = 0; i < 4; ++i) {
    const int mbase = m0 + i * 16 + quad * 4;
    float4 bias = *(const float4*)(eb3 + mbase);
    #pragma unroll
    for (int j = 0; j < 4; ++j) {
      const int n = n0 + j * 16 + l15;
      float v0 = acc[i][j][0] + bias.x;
      float v1 = acc[i][j][1] + bias.y;
      float v2 = acc[i][j][2] + bias.z;
      float v3 = acc[i][j][3] + bias.w;
      uint b0 = __float_as_uint(v0), b1 = __float_as_uint(v1);
      uint b2 = __float_as_uint(v2), b3 = __float_as_uint(v3);
      uint2 hp;
      hp.x = (b0 >> 16) | (b1 & 0xffff0000u);
      hp.y = (b2 >> 16) | (b3 & 0xffff0000u);
      float r0 = v0 - __uint_as_float(b0 & 0xffff0000u);
      float r1 = v1 - __uint_as_float(b1 & 0xffff0000u);
      float r2 = v2 - __uint_as_float(b2 & 0xffff0000u);
      float r3 = v3 - __uint_as_float(b3 & 0xffff0000u);
      uint2 lp;
      lp.x = (__float_as_uint(r0) >> 16) | (__float_as_uint(r1) & 0xffff0000u);
      lp.y = (__float_as_uint(r2) >> 16) | (__float_as_uint(r3) & 0xffff0000u);
      long off = (long)n * C3 + mbase;
      *(uint2*)(h3h + off) = hp;
      *(uint2*)(h3l + off) = lp;
    }
  }
}

// ---------------- S2: scores = cbn - 2*cb.h3^T, 3xBF16 MFMA, no-LDS 1-wave blocks --
__global__ __launch_bounds__(64) void gemm_scores(const float* __restrict__ cb,
    const ushort* __restrict__ h3h, const ushort* __restrict__ h3l,
    const float* __restrict__ cbn, float* __restrict__ scores) {
  const int t = threadIdx.x;
  const int l15 = t & 15, quad = t >> 4;
  const int m0 = blockIdx.x * 64, n0 = blockIdx.y * 64, z = blockIdx.z;
  f32x4 acc[4][4] = {};
  const float*  aB = cb + (long)z * VOC * DIMV + (long)(m0 + l15) * 512 + quad * 8;
  const ushort* bhB = h3h + (long)(n0 + l15) * C3 + z * 512 + quad * 8;
  const ushort* blB = h3l + (long)(n0 + l15) * C3 + z * 512 + quad * 8;
  for (int k0 = 0; k0 < 512; k0 += 32) {
    short8 ah[4], al[4], bh[4], bl[4];
    #pragma unroll
    for (int f = 0; f < 4; ++f) {
      const float* ap = aB + (long)f * 16 * 512 + k0;
      float4 x0 = *(const float4*)ap;
      float4 x1 = *(const float4*)(ap + 4);
      split8(x0, x1, ah[f], al[f]);
      bh[f] = *(const short8*)(bhB + (long)f * 16 * C3 + k0);
      bl[f] = *(const short8*)(blB + (long)f * 16 * C3 + k0);
    }
    #pragma unroll
    for (int i = 0; i < 4; ++i)
      #pragma unroll
      for (int j = 0; j < 4; ++j) {
        acc[i][j] = __builtin_amdgcn_mfma_f32_16x16x32_bf16(ah[i], bh[j], acc[i][j], 0, 0, 0);
        acc[i][j] = __builtin_amdgcn_mfma_f32_16x16x32_bf16(ah[i], bl[j], acc[i][j], 0, 0, 0);
        acc[i][j] = __builtin_amdgcn_mfma_f32_16x16x32_bf16(al[i], bh[j], acc[i][j], 0, 0, 0);
      }
  }
  #pragma unroll
  for (int i = 0; i < 4; ++i) {
    const int vbase = m0 + i * 16 + quad * 4;
    float4 cn = *(const float4*)(cbn + z * VOC + vbase);
    #pragma unroll
    for (int j = 0; j < 4; ++j) {
      const int n = n0 + j * 16 + l15;
      float4 out;
      out.x = cn.x - 2.f * acc[i][j][0];
      out.y = cn.y - 2.f * acc[i][j][1];
      out.z = cn.z - 2.f * acc[i][j][2];
      out.w = cn.w - 2.f * acc[i][j][3];
      *(float4*)(scores + ((long)z * NN + n) * VOC + vbase) = out;
    }
  }
}

// ---------------- argmin over 1024 codes, numpy tie-break (lowest v) ----------------
__global__ void k_argmin(const float* __restrict__ scores, int* __restrict__ codes) {
  int row = blockIdx.x;          // k*256+n
  int lane = threadIdx.x;        // 64
  const float* p = scores + (long)row * VOC;
  float best = 3.4e38f; int bi = 0;
  for (int i = 0; i < 16; ++i) {
    int v = i * 64 + lane;
    float x = p[v];
    if (x < best) { best = x; bi = v; }
  }
  for (int off = 32; off; off >>= 1) {
    float ob = __shfl_down(best, off);
    int oi = __shfl_down(bi, off);
    if (ob < best || (ob == best && oi < bi)) { best = ob; bi = oi; }
  }
  if (lane == 0) codes[row] = bi;
}

// ---------------- transpose+convert dw1 [7168][2560] fp32 -> dw1t [2560][7168] bf16 ----
__global__ __launch_bounds__(256) void k_dw1t(const float* __restrict__ dw1,
                                              ushort* __restrict__ dw1t) {
  __shared__ __align__(16) ushort T[64 * 72];   // [m][k] tile, pitch 72
  int t = threadIdx.x;
  int k0 = blockIdx.x * 64, m0 = blockIdx.y * 64;
  int kk = t >> 2, mj = (t & 3) * 16;
  const float* src = dw1 + (long)(k0 + kk) * 2560 + m0 + mj;
  float x[16];
  *(float4*)&x[0]  = *(const float4*)(src);
  *(float4*)&x[4]  = *(const float4*)(src + 4);
  *(float4*)&x[8]  = *(const float4*)(src + 8);
  *(float4*)&x[12] = *(const float4*)(src + 12);
  #pragma unroll
  for (int l = 0; l < 16; ++l)
    T[(mj + l) * 72 + kk] = f2bf(x[l]);
  __syncthreads();
  int mo = t >> 2, kc = (t & 3) * 16;
  uint4 u0 = *(const uint4*)&T[mo * 72 + kc];
  uint4 u1 = *(const uint4*)&T[mo * 72 + kc + 8];
  ushort* dst = dw1t + (long)(m0 + mo) * C3 + k0 + kc;
  *(uint4*)dst = u0;
  *(uint4*)(dst + 8) = u1;
}

// ---------------- gather q as bf16: qbf[n][k*512+d] = bf16(cb[k, code, d]) ----------
__global__ void k_gather_qbf(const float* __restrict__ cb, const int* __restrict__ codes,
                             ushort* __restrict__ qbf) {
  int idx = blockIdx.x * 256 + threadIdx.x;      // pair index
  const int total = NN * C3 / 2;                 // 917504
  if (idx >= total) return;
  int n = idx / 3584, rr = idx - n * 3584;       // rr = k*256 + dp
  int k = rr >> 8, dp = rr & 255;
  int code = codes[k * NN + n];
  const float* s = cb + ((long)(k * VOC + code)) * DIMV + dp * 2;
  uint lo = f2bf(s[0]), hi = f2bf(s[1]);
  ((uint*)qbf)[idx] = lo | (hi << 16);
}

// ---------------- decoder convT GEMM via MFMA bf16 ----------------
__global__ __launch_bounds__(256) void gemm_a1_mfma(const ushort* __restrict__ dw1t,
    const ushort* __restrict__ qbf, float* __restrict__ a1raw) {
  __shared__ __align__(16) ushort As[64 * 40];
  __shared__ __align__(16) ushort Bs[64 * 40];
  const int tid = threadIdx.x;
  const int w = tid >> 6, lane = tid & 63;
  const int wm = w & 1, wn = w >> 1;
  const int m0 = blockIdx.x * 64, n0 = blockIdx.y * 64;
  const int l15 = lane & 15, quad = lane >> 4;
  const int r = tid >> 2, koff = (tid & 3) * 8;
  const ushort* aP = dw1t + (long)(m0 + r) * C3 + koff;
  const ushort* bP = qbf + (long)(n0 + r) * C3 + koff;
  f32x4 acc[2][2] = {};
  const int aoff0 = (wm * 32 + l15) * 40 + quad * 8;
  const int aoff1 = (wm * 32 + 16 + l15) * 40 + quad * 8;
  const int boff0 = (wn * 32 + l15) * 40 + quad * 8;
  const int boff1 = (wn * 32 + 16 + l15) * 40 + quad * 8;
  const int soff = r * 40 + koff;
  for (int k0 = 0; k0 < C3; k0 += 32) {
    uint4 av = *(const uint4*)(aP + k0);
    uint4 bv = *(const uint4*)(bP + k0);
    *(uint4*)&As[soff] = av;
    *(uint4*)&Bs[soff] = bv;
    __syncthreads();
    short8 a0 = *(const short8*)&As[aoff0];
    short8 a1 = *(const short8*)&As[aoff1];
    short8 b0 = *(const short8*)&Bs[boff0];
    short8 b1 = *(const short8*)&Bs[boff1];
    acc[0][0] = __builtin_amdgcn_mfma_f32_16x16x32_bf16(a0, b0, acc[0][0], 0, 0, 0);
    acc[0][1] = __builtin_amdgcn_mfma_f32_16x16x32_bf16(a0, b1, acc[0][1], 0, 0, 0);
    acc[1][0] = __builtin_amdgcn_mfma_f32_16x16x32_bf16(a1, b0, acc[1][0], 0, 0, 0);
    acc[1][1] = __builtin_amdgcn_mfma_f32_16x16x32_bf16(a1, b1, acc[1][1], 0, 0, 0);
    __syncthreads();
  }
  #pragma unroll
  for (int i = 0; i < 2; ++i)
    #pragma unroll
    for (int j = 0; j < 2; ++j)
      #pragma unroll
      for (int reg = 0; reg < 4; ++reg) {
        int m = m0 + wm * 32 + i * 16 + quad * 4 + reg;
        int n = n0 + wn * 32 + j * 16 + l15;
        int c = m / 5, jj = m - c * 5;
        a1raw[((long)(n * 5 + jj)) * C2 + c] = acc[i][j][reg];
      }
}

// ---------------- k_x2: build conv2 im2col X (bf16 hi/lo) from a1raw/ab1 ----------
__global__ void k_x2(const float* __restrict__ a1raw, const float* __restrict__ ab1g,
                     const float* __restrict__ db1, ushort* __restrict__ Xh,
                     ushort* __restrict__ Xl) {
  int idx = blockIdx.x * 256 + threadIdx.x;
  const int total = 2304 * 2560;
  for (; idx < total; idx += gridDim.x * 256) {
    int nu = idx / 2560, ck = idx - nu * 2560;
    int n = nu / 9, u = nu - n * 9;
    int c = ck / 5, jj = ck - c * 5;
    int w = u + jj;
    int s = n & 127;
    int tc = HOP * s - 6 + w;
    float v;
    if (tc < 0 || tc > TOUT - 1) v = 0.f;
    else if (w >= 4 && w <= 8)
      v = fmaxf(db1[c] + a1raw[((long)(n * 5 + (w - 4))) * C2 + c], 0.f);
    else v = ab1g[c];
    uint bi = __float_as_uint(v);
    Xh[idx] = (ushort)(bi >> 16);
    float rr = v - __uint_as_float(bi & 0xffff0000u);
    Xl[idx] = (ushort)(__float_as_uint(rr) >> 16);
  }
}

// ---------------- decoder conv2 as GEMM: a2act = relu(db2 + dw2 . X^T) ----------
__global__ __launch_bounds__(64) void gemm_dec2(const float* __restrict__ dw2,
    const ushort* __restrict__ Xh, const ushort* __restrict__ Xl,
    const float* __restrict__ db2, float* __restrict__ a2act) {
  const int t = threadIdx.x;
  const int l15 = t & 15, quad = t >> 4;
  const int m0 = blockIdx.x * 64, n0 = blockIdx.y * 64;
  f32x4 acc[4][4] = {};
  const float*  aB = dw2 + (long)(m0 + l15) * 2560 + quad * 8;
  const ushort* bhB = Xh + (long)(n0 + l15) * 2560 + quad * 8;
  const ushort* blB = Xl + (long)(n0 + l15) * 2560 + quad * 8;
  for (int k0 = 0; k0 < 2560; k0 += 32) {
    short8 ah[4], al[4], bh[4], bl[4];
    #pragma unroll
    for (int f = 0; f < 4; ++f) {
      const float* ap = aB + (long)f * 16 * 2560 + k0;
      float4 x0 = *(const float4*)ap;
      float4 x1 = *(const float4*)(ap + 4);
      split8(x0, x1, ah[f], al[f]);
      bh[f] = *(const short8*)(bhB + (long)f * 16 * 2560 + k0);
      bl[f] = *(const short8*)(blB + (long)f * 16 * 2560 + k0);
    }
    #pragma unroll
    for (int i = 0; i < 4; ++i)
      #pragma unroll
      for (int j = 0; j < 4; ++j) {
        acc[i][j] = __builtin_amdgcn_mfma_f32_16x16x32_bf16(ah[i], bh[j], acc[i][j], 0, 0, 0);
        acc[i][j] = __builtin_amdgcn_mfma_f32_16x16x32_bf16(ah[i], bl[j], acc[i][j], 0, 0, 0);
        acc[i][j] = __builtin_amdgcn_mfma_f32_16x16x32_bf16(al[i], bh[j], acc[i][j], 0, 0, 0);
      }
  }
  #pragma unroll
  for (int i = 0; i < 4; ++i) {
    const int obase = m0 + i * 16 + quad * 4;
    float4 bias = *(const float4*)(db2 + obase);
    #pragma unroll
    for (int j = 0; j < 4; ++j) {
      const int nu = n0 + j * 16 + l15;
      float4 out;
      out.x = fmaxf(acc[i][j][0] + bias.x, 0.f);
      out.y = fmaxf(acc[i][j][1] + bias.y, 0.f);
      out.z = fmaxf(acc[i][j][2] + bias.z, 0.f);
      out.w = fmaxf(acc[i][j][3] + bias.w, 0.f);
      *(float4*)(a2act + (long)nu * C1 + obase) = out;
    }
  }
}

// ---------------- fill output with the constant tanh value ----------------
__global__ void k_fill(float* __restrict__ outp, const float* __restrict__ cconst) {
  float v = cconst[0];
  int idx = blockIdx.x * 256 + threadIdx.x;
  const int total = NBATCH * TOUT;
  for (; idx < total; idx += gridDim.x * 256) outp[idx] = v;
}

// ---------------- decoder conv3+tanh on 15 active cols per (b,s) ----------------
__global__ __launch_bounds__(256) void k_dec3(const float* __restrict__ a2act,
    const float* __restrict__ ab2g, const float* __restrict__ dw3,
    const float* __restrict__ db3, float* __restrict__ outp) {
  __shared__ float sa2[9 * C1];
  __shared__ float sb[C1];
  int n = blockIdx.x;
  int s = n & 127, b = n >> 7;
  int t = threadIdx.x;
  for (int i = t; i < 9 * C1; i += 256) sa2[i] = a2act[(long)n * 9 * C1 + i];
  sb[t] = ab2g[t];
  __syncthreads();
  int wv = t >> 6, lane = t & 63;
  float b3 = db3[0];
  for (int w15 = wv; w15 < 15; w15 += 4) {
    int tc = HOP * s - 7 + w15;
    if (tc < 0 || tc > TOUT - 1) continue;
    float part = 0.f;
    for (int cc = lane; cc < C1; cc += 64) {
      #pragma unroll
      for (int j = 0; j < 7; ++j) {
        int wcol = tc + j - 3;
        float x;
        if (wcol < 0 || wcol > TOUT - 1) x = 0.f;
        else {
          int du = wcol - (HOP * s - 4);
          x = (du >= 0 && du <= 8) ? sa2[du * C1 + cc] : sb[cc];
        }
        part = fmaf(dw3[cc*7+j], x, part);
      }
    }
    for (int off = 32; off; off >>= 1) part += __shfl_down(part, off);
    if (lane == 0) outp[(long)b * TOUT + tc] = tanhf(part + b3);
  }
}

extern "C" void kernel_launch(void* const* d_in, const int* in_sizes, int n_in,
                              void* d_out, int out_size, void* d_ws, size_t ws_size,
                              hipStream_t stream) {
  const float* audio = (const float*)d_in[0];
  const float* cb    = (const float*)d_in[1];
  const float* ew1   = (const float*)d_in[2];
  const float* eb1   = (const float*)d_in[3];
  const float* ew2   = (const float*)d_in[4];
  const float* eb2   = (const float*)d_in[5];
  const float* ew3   = (const float*)d_in[6];
  const float* eb3   = (const float*)d_in[7];
  const float* dw1   = (const float*)d_in[8];
  const float* db1   = (const float*)d_in[9];
  const float* dw2   = (const float*)d_in[10];
  const float* db2   = (const float*)d_in[11];
  const float* dw3   = (const float*)d_in[12];
  const float* db3   = (const float*)d_in[13];
  float* outp = (float*)d_out;
  float* ws = (float*)d_ws;

  float*  cbn    = ws + OFF_CBN;
  float*  ab1    = ws + OFF_AB1;
  float*  ab2    = ws + OFF_AB2;
  float*  cconst = ws + OFF_CCONST;
  float*  h2c    = ws + OFF_H2C;
  ushort* h2xh   = (ushort*)(ws + OFF_H2XH);
  ushort* h2xl   = (ushort*)(ws + OFF_H2XL);
  ushort* h3h    = (ushort*)(ws + OFF_H3H);
  ushort* h3l    = (ushort*)(ws + OFF_H3L);
  float*  scores = ws + OFF_SCORES;
  ushort* X1h    = (ushort*)(ws + OFF_X1H);
  ushort* X1l    = (ushort*)(ws + OFF_X1L);
  ushort* dw1t   = (ushort*)(ws + OFF_DW1T);
  ushort* Xh     = (ushort*)(ws + OFF_XH);
  ushort* Xl     = (ushort*)(ws + OFF_XL);
  int*    codes  = (int*)(ws + OFF_CODES);
  ushort* qbf    = (ushort*)(ws + OFF_QBF);
  float*  a1raw  = ws + OFF_A1RAW;
  float*  a2act  = ws + OFF_A2ACT;

  k_cbn<<<3584, 256, 0, stream>>>(cb, cbn);
  k_prep_ab2<<<C1, 256, 0, stream>>>(db1, dw2, db2, ab1, ab2);
  k_prep_c<<<1, 256, 0, stream>>>(dw3, db3, ab2, cconst);
  k_enc1<<<NN, 256, 0, stream>>>(audio, ew1, eb1, X1h, X1l);
  gemm_enc2<<<dim3(16, 4), 64, 0, stream>>>(ew2, X1h, X1l, eb2, h2c);
  k_h2x<<<384, 256, 0, stream>>>(h2c, h2xh, h2xl);
  gemm_h3<<<dim3(112, 4), 64, 0, stream>>>(ew3, h2xh, h2xl, eb3, h3h, h3l);
  // gemm_scores writes over X1h/X1l (dead after gemm_enc2) — stream-ordered
  gemm_scores<<<dim3(16, 4, 14), 64, 0, stream>>>(cb, h3h, h3l, cbn, scores);
  k_argmin<<<NCBK * NN, 64, 0, stream>>>(scores, codes);
  // dw1t overlaps h3h/h3l/scores memory: must launch AFTER k_argmin (stream-ordered)
  k_dw1t<<<dim3(112, 40), 256, 0, stream>>>(dw1, dw1t);
  k_gather_qbf<<<3584, 256, 0, stream>>>(cb, codes, qbf);
  gemm_a1_mfma<<<dim3(40, 4), 256, 0, stream>>>(dw1t, qbf, a1raw);
  // Xh/Xl overlap dw1t memory: must launch AFTER gemm_a1_mfma (stream-ordered)
  k_x2<<<4096, 256, 0, stream>>>(a1raw, ab1, db1, Xh, Xl);
  gemm_dec2<<<dim3(4, 36), 64, 0, stream>>>(dw2, Xh, Xl, db2, a2act);
  k_fill<<<256, 256, 0, stream>>>(outp, cconst);
  k_dec3<<<NN, 256, 0, stream>>>(a2act, ab2, dw3, db3, outp);
}